// Round 4
// baseline (763.263 us; speedup 1.0000x reference)
//
#include <hip/hip_runtime.h>
#include <hip/hip_bf16.h>

typedef __hip_bfloat16 bf16_t;
typedef float f32x4 __attribute__((ext_vector_type(4)));
typedef __bf16 bf16x8 __attribute__((ext_vector_type(8)));

#define AS1 __attribute__((address_space(1)))
#define AS3 __attribute__((address_space(3)))

__device__ __forceinline__ void gload_lds16(const void* g, void* l) {
  __builtin_amdgcn_global_load_lds((const AS1 void*)g, (AS3 void*)l, 16, 0, 0);
}

__device__ __forceinline__ bf16_t f2b(float v) { return __float2bfloat16(v); }
__device__ __forceinline__ float b2f(bf16_t v) { return __bfloat162float(v); }

// ------------- adj = softmax(relu(E E^T), axis=1), hi/lo bf16 planes -------
__global__ __launch_bounds__(256) void adj_softmax(const float* __restrict__ emb,
                                                   bf16_t* __restrict__ adjH,
                                                   bf16_t* __restrict__ adjL) {
  __shared__ float vals[2048];
  __shared__ float red[16];
  const int n = blockIdx.x;
  const int t = threadIdx.x;
  const int lane = t & 63, wave = t >> 6;
  float en[10];
#pragma unroll
  for (int e = 0; e < 10; ++e) en[e] = emb[n * 10 + e];
  float lm = 0.0f;
  for (int m = t; m < 2048; m += 256) {
    const float* em = emb + m * 10;
    float d = 0.f;
#pragma unroll
    for (int e = 0; e < 10; ++e) d += en[e] * em[e];
    d = fmaxf(d, 0.0f);
    vals[m] = d;
    lm = fmaxf(lm, d);
  }
#pragma unroll
  for (int off = 32; off > 0; off >>= 1) lm = fmaxf(lm, __shfl_down(lm, off));
  if (lane == 0) red[wave] = lm;
  __syncthreads();
  const float gmax = fmaxf(fmaxf(red[0], red[1]), fmaxf(red[2], red[3]));
  float ls = 0.f;
  for (int m = t; m < 2048; m += 256) {
    float ev = expf(vals[m] - gmax);
    vals[m] = ev;
    ls += ev;
  }
#pragma unroll
  for (int off = 32; off > 0; off >>= 1) ls += __shfl_down(ls, off);
  if (lane == 0) red[8 + wave] = ls;
  __syncthreads();
  const float inv = 1.0f / (red[8] + red[9] + red[10] + red[11]);
  for (int m = t; m < 2048; m += 256) {
    float v = vals[m] * inv;
    bf16_t h = f2b(v);
    adjH[(long)n * 2048 + m] = h;
    adjL[(long)n * 2048 + m] = f2b(v - b2f(h));
  }
}

// ------------- XT[b*64+i][m] = x[b][m][i], hi/lo planes --------------------
__global__ __launch_bounds__(256) void split_xt(const float* __restrict__ x,
                                                bf16_t* __restrict__ XTh,
                                                bf16_t* __restrict__ XTl) {
  __shared__ float tile[64][65];
  const int m0 = blockIdx.x * 64;
  const int b = blockIdx.y;
  const int tx = threadIdx.x & 63, ty = threadIdx.x >> 6;
  for (int r = ty; r < 64; r += 4)
    tile[r][tx] = x[(long)b * 131072 + (long)(m0 + r) * 64 + tx];
  __syncthreads();
  for (int r = ty; r < 64; r += 4) {
    float v = tile[tx][r];
    bf16_t h = f2b(v);
    long idx = (long)(b * 64 + r) * 2048 + m0 + tx;
    XTh[idx] = h;
    XTl[idx] = f2b(v - b2f(h));
  }
}

// ------------- generic fp32 transpose-split: out[c][r] = in[r][c] ----------
__global__ __launch_bounds__(256) void tsplit(const float* __restrict__ in,
                                              bf16_t* __restrict__ oH,
                                              bf16_t* __restrict__ oL, int R, int C) {
  __shared__ float tile[64][65];
  const int c0 = blockIdx.x * 64, r0 = blockIdx.y * 64;
  const int tx = threadIdx.x & 63, ty = threadIdx.x >> 6;
  for (int r = ty; r < 64; r += 4)
    tile[r][tx] = in[(long)(r0 + r) * C + c0 + tx];
  __syncthreads();
  for (int r = ty; r < 64; r += 4) {
    float v = tile[tx][r];
    bf16_t h = f2b(v);
    long idx = (long)(c0 + r) * R + r0 + tx;
    oH[idx] = h;
    oL[idx] = f2b(v - b2f(h));
  }
}

// ------------- Cnf[n][b*128+i] = x[b][n][i] (i<64), fp32 -------------------
__global__ __launch_bounds__(256) void cnf_x(const float* __restrict__ x,
                                             float* __restrict__ Cnf) {
  const int n = blockIdx.x;
  const int t = threadIdx.x;
  const int idx = t * 8;
  const int b = idx >> 6, i = idx & 63;
  const float* xp = x + (long)b * 131072 + (long)n * 64 + i;
  float4 v0 = *(const float4*)(xp);
  float4 v1 = *(const float4*)(xp + 4);
  float* dst = Cnf + (long)n * 4096 + b * 128 + i;
  *(float4*)dst = v0;
  *(float4*)(dst + 4) = v1;
}

// ------------- permute w_pool (E,3,I,O) -> P[e][o*KI + k*I+i], fp32 --------
__global__ __launch_bounds__(256) void permute_pool(const float* __restrict__ wp,
                                                    float* __restrict__ P,
                                                    int KI, int I, int O) {
  const int g = blockIdx.x * 256 + threadIdx.x;
  const int per = KI * O;  // 24576
  const int e = g / per, rem = g % per;
  const int o = rem / KI, kk = rem % KI;
  const int k = kk / I, i = kk % I;
  P[g] = wp[(long)((e * 3 + k) * I + i) * O + o];
}

// ------------- fused multi-product GEMM: C[i,j] = sum_k A[i,k]*B[j,k] ------
// products: Ah*Bh (+ Ah*Bl if BLO) (+ Al*Bh if ALO).  fp32 C.
// EPI 0: C=v   EPI 1: C=2v - x[b][gm][i] (gn=b*64+i)   EPI 2: C=2v - sub[gm*ldc+gn]
template <int ALO, int BLO, int EPI>
__global__ __launch_bounds__(256) void fgemm(const bf16_t* __restrict__ Ah,
                                             const bf16_t* __restrict__ Al,
                                             const bf16_t* __restrict__ Bh,
                                             const bf16_t* __restrict__ Bl,
                                             float* __restrict__ Cf, int K, int ldc,
                                             const float* __restrict__ xsrc,
                                             const float* __restrict__ sub) {
  __shared__ __align__(16) bf16_t Ash[128 * 32];
  __shared__ __align__(16) bf16_t Asl[128 * 32];
  __shared__ __align__(16) bf16_t Bsh[128 * 32];
  __shared__ __align__(16) bf16_t Bsl[128 * 32];
  const int t = threadIdx.x;
  const int wave = t >> 6, lane = t & 63;
  const long m0 = (long)blockIdx.y * 128;
  const long n0 = (long)blockIdx.x * 128;
  const int srow = t >> 2;
  const int skb = (t & 3) * 8;
  const long soff = (m0 + srow) * K + skb;
  const long soffB = (n0 + srow) * K + skb;
  const int wm = (wave >> 1) * 64;
  const int wn = (wave & 1) * 64;
  const int fr = lane & 15, qk = (lane >> 4) * 8;
  char* lAh = (char*)Ash + wave * 1024;
  char* lAl = (char*)Asl + wave * 1024;
  char* lBh = (char*)Bsh + wave * 1024;
  char* lBl = (char*)Bsl + wave * 1024;
  f32x4 acc[4][4] = {};
  for (int k0 = 0; k0 < K; k0 += 32) {
    gload_lds16(Ah + soff + k0, lAh);
    gload_lds16(Ah + soff + (long)64 * K + k0, lAh + 4096);
    gload_lds16(Bh + soffB + k0, lBh);
    gload_lds16(Bh + soffB + (long)64 * K + k0, lBh + 4096);
    if (ALO) {
      gload_lds16(Al + soff + k0, lAl);
      gload_lds16(Al + soff + (long)64 * K + k0, lAl + 4096);
    }
    if (BLO) {
      gload_lds16(Bl + soffB + k0, lBl);
      gload_lds16(Bl + soffB + (long)64 * K + k0, lBl + 4096);
    }
    __syncthreads();
    bf16x8 afh[4], bvh[4];
#pragma unroll
    for (int i = 0; i < 4; ++i) {
      afh[i] = *(const bf16x8*)(Ash + (wm + i * 16 + fr) * 32 + qk);
      bvh[i] = *(const bf16x8*)(Bsh + (wn + i * 16 + fr) * 32 + qk);
    }
#pragma unroll
    for (int i = 0; i < 4; ++i)
#pragma unroll
      for (int j = 0; j < 4; ++j)
        acc[i][j] = __builtin_amdgcn_mfma_f32_16x16x32_bf16(afh[i], bvh[j], acc[i][j], 0, 0, 0);
    if (BLO) {
      bf16x8 bvl[4];
#pragma unroll
      for (int j = 0; j < 4; ++j)
        bvl[j] = *(const bf16x8*)(Bsl + (wn + j * 16 + fr) * 32 + qk);
#pragma unroll
      for (int i = 0; i < 4; ++i)
#pragma unroll
        for (int j = 0; j < 4; ++j)
          acc[i][j] = __builtin_amdgcn_mfma_f32_16x16x32_bf16(afh[i], bvl[j], acc[i][j], 0, 0, 0);
    }
    if (ALO) {
      bf16x8 afl[4];
#pragma unroll
      for (int i = 0; i < 4; ++i)
        afl[i] = *(const bf16x8*)(Asl + (wm + i * 16 + fr) * 32 + qk);
#pragma unroll
      for (int i = 0; i < 4; ++i)
#pragma unroll
        for (int j = 0; j < 4; ++j)
          acc[i][j] = __builtin_amdgcn_mfma_f32_16x16x32_bf16(afl[i], bvh[j], acc[i][j], 0, 0, 0);
    }
    __syncthreads();
  }
  const int crow = (lane >> 4) * 4, ccol = lane & 15;
#pragma unroll
  for (int i = 0; i < 4; ++i)
#pragma unroll
    for (int j = 0; j < 4; ++j)
#pragma unroll
      for (int r = 0; r < 4; ++r) {
        long gm = m0 + wm + i * 16 + crow + r;
        long gn = n0 + wn + j * 16 + ccol;
        float v = acc[i][j][r];
        if (EPI == 0) Cf[gm * ldc + gn] = v;
        if (EPI == 1)
          Cf[gm * ldc + gn] =
              2.0f * v - xsrc[(long)(gn >> 6) * 131072 + gm * 64 + (gn & 63)];
        if (EPI == 2) Cf[gm * ldc + gn] = 2.0f * v - sub[gm * ldc + gn];
      }
}

// ------------- gate: (32x192)@W_n(192x128)+bias, sigmoid -------------------
// A = [x | Xg1 | Xg2] fp32 -> hi/lo.  W_n = emb[n]@P generated in-kernel, hi/lo.
// z -> Cnf[:,64:] (fp32), r -> rbf (fp32).
__global__ __launch_bounds__(256) void gate_kernel(
    const float* __restrict__ x, const float* __restrict__ Xg1f,
    const float* __restrict__ Xg2f, const float* __restrict__ P,
    const float* __restrict__ bpool, const float* __restrict__ emb,
    float* __restrict__ Cnf, float* __restrict__ rbf) {
  __shared__ __align__(16) bf16_t Ahi[32 * 200];
  __shared__ __align__(16) bf16_t Alo[32 * 200];
  __shared__ __align__(16) bf16_t Whi[128 * 200];
  __shared__ __align__(16) bf16_t Wlo[128 * 200];
  const int n = blockIdx.x;
  const int t = threadIdx.x;
  float en[10];
#pragma unroll
  for (int e = 0; e < 10; ++e) en[e] = emb[n * 10 + e];
  // ---- stage A (hi/lo) ----
  {
    const int b = t >> 3, i8 = (t & 7) * 8;
    const float* s[3];
    s[0] = x + (long)b * 131072 + (long)n * 64 + i8;
    s[1] = Xg1f + (long)n * 2048 + b * 64 + i8;
    s[2] = Xg2f + (long)n * 2048 + b * 64 + i8;
#pragma unroll
    for (int sec = 0; sec < 3; ++sec) {
      union { uint4 u; bf16_t h[8]; } th, tl;
#pragma unroll
      for (int j = 0; j < 8; ++j) {
        float v = s[sec][j];
        bf16_t h = f2b(v);
        th.h[j] = h;
        tl.h[j] = f2b(v - b2f(h));
      }
      *(uint4*)(Ahi + b * 200 + sec * 64 + i8) = th.u;
      *(uint4*)(Alo + b * 200 + sec * 64 + i8) = tl.u;
    }
  }
  // ---- generate W_n = sum_e en[e] * P[e][:], split hi/lo ----
#pragma unroll
  for (int r = 0; r < 12; ++r) {
    const int c = r * 2048 + t * 8;
    float v[8] = {0, 0, 0, 0, 0, 0, 0, 0};
#pragma unroll
    for (int e = 0; e < 10; ++e) {
      const float4 p0 = *(const float4*)(P + (long)e * 24576 + c);
      const float4 p1 = *(const float4*)(P + (long)e * 24576 + c + 4);
      v[0] += en[e] * p0.x; v[1] += en[e] * p0.y;
      v[2] += en[e] * p0.z; v[3] += en[e] * p0.w;
      v[4] += en[e] * p1.x; v[5] += en[e] * p1.y;
      v[6] += en[e] * p1.z; v[7] += en[e] * p1.w;
    }
    const int o = c / 192, kk = c % 192;
    union { uint4 u; bf16_t h[8]; } th, tl;
#pragma unroll
    for (int j = 0; j < 8; ++j) {
      bf16_t h = f2b(v[j]);
      th.h[j] = h;
      tl.h[j] = f2b(v[j] - b2f(h));
    }
    *(uint4*)(Whi + o * 200 + kk) = th.u;
    *(uint4*)(Wlo + o * 200 + kk) = tl.u;
  }
  __syncthreads();
  const int wave = t >> 6, lane = t & 63;
  const int ob = wave * 32;
  const int fr = lane & 15, qk = (lane >> 4) * 8;
  f32x4 acc[2][2] = {};
#pragma unroll
  for (int k0 = 0; k0 < 192; k0 += 32) {
    bf16x8 a0h = *(const bf16x8*)(Ahi + fr * 200 + k0 + qk);
    bf16x8 a1h = *(const bf16x8*)(Ahi + (16 + fr) * 200 + k0 + qk);
    bf16x8 a0l = *(const bf16x8*)(Alo + fr * 200 + k0 + qk);
    bf16x8 a1l = *(const bf16x8*)(Alo + (16 + fr) * 200 + k0 + qk);
    bf16x8 b0h = *(const bf16x8*)(Whi + (ob + fr) * 200 + k0 + qk);
    bf16x8 b1h = *(const bf16x8*)(Whi + (ob + 16 + fr) * 200 + k0 + qk);
    bf16x8 b0l = *(const bf16x8*)(Wlo + (ob + fr) * 200 + k0 + qk);
    bf16x8 b1l = *(const bf16x8*)(Wlo + (ob + 16 + fr) * 200 + k0 + qk);
    acc[0][0] = __builtin_amdgcn_mfma_f32_16x16x32_bf16(a0h, b0h, acc[0][0], 0, 0, 0);
    acc[0][0] = __builtin_amdgcn_mfma_f32_16x16x32_bf16(a0l, b0h, acc[0][0], 0, 0, 0);
    acc[0][0] = __builtin_amdgcn_mfma_f32_16x16x32_bf16(a0h, b0l, acc[0][0], 0, 0, 0);
    acc[1][0] = __builtin_amdgcn_mfma_f32_16x16x32_bf16(a1h, b0h, acc[1][0], 0, 0, 0);
    acc[1][0] = __builtin_amdgcn_mfma_f32_16x16x32_bf16(a1l, b0h, acc[1][0], 0, 0, 0);
    acc[1][0] = __builtin_amdgcn_mfma_f32_16x16x32_bf16(a1h, b0l, acc[1][0], 0, 0, 0);
    acc[0][1] = __builtin_amdgcn_mfma_f32_16x16x32_bf16(a0h, b1h, acc[0][1], 0, 0, 0);
    acc[0][1] = __builtin_amdgcn_mfma_f32_16x16x32_bf16(a0l, b1h, acc[0][1], 0, 0, 0);
    acc[0][1] = __builtin_amdgcn_mfma_f32_16x16x32_bf16(a0h, b1l, acc[0][1], 0, 0, 0);
    acc[1][1] = __builtin_amdgcn_mfma_f32_16x16x32_bf16(a1h, b1h, acc[1][1], 0, 0, 0);
    acc[1][1] = __builtin_amdgcn_mfma_f32_16x16x32_bf16(a1l, b1h, acc[1][1], 0, 0, 0);
    acc[1][1] = __builtin_amdgcn_mfma_f32_16x16x32_bf16(a1h, b1l, acc[1][1], 0, 0, 0);
  }
  const int quad = lane >> 4;
#pragma unroll
  for (int j = 0; j < 2; ++j) {
    const int o = ob + j * 16 + fr;
    float bias = 0.f;
#pragma unroll
    for (int e = 0; e < 10; ++e) bias += en[e] * bpool[e * 128 + o];
#pragma unroll
    for (int i2 = 0; i2 < 2; ++i2)
#pragma unroll
      for (int r = 0; r < 4; ++r) {
        const int b = i2 * 16 + quad * 4 + r;
        float v = acc[i2][j][r] + bias;
        v = 1.0f / (1.0f + expf(-v));
        if (o < 64)
          Cnf[(long)n * 4096 + b * 128 + 64 + o] = v;  // z
        else
          rbf[(long)n * 2048 + b * 64 + (o - 64)] = v;  // r
      }
  }
}

// ------------- update: (32x384)@W_n(384x64), tanh, GRU blend ---------------
// A = [cand | Cg1 | Cg2] all fp32 -> hi/lo.  W_n in-kernel, hi/lo.
__global__ __launch_bounds__(256) void update_kernel(
    const float* __restrict__ x, const float* __restrict__ Cnf,
    const float* __restrict__ Cg1f, const float* __restrict__ Cg2f,
    const float* __restrict__ P, const float* __restrict__ bpool,
    const float* __restrict__ emb, const float* __restrict__ rbf,
    float* __restrict__ out) {
  __shared__ __align__(16) bf16_t Ahi[32 * 392];
  __shared__ __align__(16) bf16_t Alo[32 * 392];
  __shared__ __align__(16) bf16_t Whi[64 * 392];
  __shared__ __align__(16) bf16_t Wlo[64 * 392];
  const int n = blockIdx.x;
  const int t = threadIdx.x;
  float en[10];
#pragma unroll
  for (int e = 0; e < 10; ++e) en[e] = emb[n * 10 + e];
  // ---- stage A (hi/lo), 3 fp32 sources ----
#pragma unroll
  for (int r = 0; r < 2; ++r) {
    const int c = r * 2048 + t * 8;
    const int b = c >> 7, j = c & 127;
    const float* s[3];
    s[0] = Cnf + (long)n * 4096 + c;
    s[1] = Cg1f + (long)n * 4096 + c;
    s[2] = Cg2f + (long)n * 4096 + c;
#pragma unroll
    for (int sec = 0; sec < 3; ++sec) {
      union { uint4 u; bf16_t h[8]; } th, tl;
#pragma unroll
      for (int q = 0; q < 8; ++q) {
        float v = s[sec][q];
        bf16_t h = f2b(v);
        th.h[q] = h;
        tl.h[q] = f2b(v - b2f(h));
      }
      *(uint4*)(Ahi + b * 392 + sec * 128 + j) = th.u;
      *(uint4*)(Alo + b * 392 + sec * 128 + j) = tl.u;
    }
  }
  // ---- generate W_n, split hi/lo ----
#pragma unroll
  for (int r = 0; r < 12; ++r) {
    const int c = r * 2048 + t * 8;
    float v[8] = {0, 0, 0, 0, 0, 0, 0, 0};
#pragma unroll
    for (int e = 0; e < 10; ++e) {
      const float4 p0 = *(const float4*)(P + (long)e * 24576 + c);
      const float4 p1 = *(const float4*)(P + (long)e * 24576 + c + 4);
      v[0] += en[e] * p0.x; v[1] += en[e] * p0.y;
      v[2] += en[e] * p0.z; v[3] += en[e] * p0.w;
      v[4] += en[e] * p1.x; v[5] += en[e] * p1.y;
      v[6] += en[e] * p1.z; v[7] += en[e] * p1.w;
    }
    const int o = c / 384, kk = c % 384;
    union { uint4 u; bf16_t h[8]; } th, tl;
#pragma unroll
    for (int j = 0; j < 8; ++j) {
      bf16_t h = f2b(v[j]);
      th.h[j] = h;
      tl.h[j] = f2b(v[j] - b2f(h));
    }
    *(uint4*)(Whi + o * 392 + kk) = th.u;
    *(uint4*)(Wlo + o * 392 + kk) = tl.u;
  }
  __syncthreads();
  const int wave = t >> 6, lane = t & 63;
  const int ob = wave * 16;
  const int fr = lane & 15, qk = (lane >> 4) * 8;
  f32x4 acc[2] = {};
#pragma unroll
  for (int k0 = 0; k0 < 384; k0 += 32) {
    bf16x8 a0h = *(const bf16x8*)(Ahi + fr * 392 + k0 + qk);
    bf16x8 a1h = *(const bf16x8*)(Ahi + (16 + fr) * 392 + k0 + qk);
    bf16x8 a0l = *(const bf16x8*)(Alo + fr * 392 + k0 + qk);
    bf16x8 a1l = *(const bf16x8*)(Alo + (16 + fr) * 392 + k0 + qk);
    bf16x8 b0h = *(const bf16x8*)(Whi + (ob + fr) * 392 + k0 + qk);
    bf16x8 b0l = *(const bf16x8*)(Wlo + (ob + fr) * 392 + k0 + qk);
    acc[0] = __builtin_amdgcn_mfma_f32_16x16x32_bf16(a0h, b0h, acc[0], 0, 0, 0);
    acc[0] = __builtin_amdgcn_mfma_f32_16x16x32_bf16(a0l, b0h, acc[0], 0, 0, 0);
    acc[0] = __builtin_amdgcn_mfma_f32_16x16x32_bf16(a0h, b0l, acc[0], 0, 0, 0);
    acc[1] = __builtin_amdgcn_mfma_f32_16x16x32_bf16(a1h, b0h, acc[1], 0, 0, 0);
    acc[1] = __builtin_amdgcn_mfma_f32_16x16x32_bf16(a1l, b0h, acc[1], 0, 0, 0);
    acc[1] = __builtin_amdgcn_mfma_f32_16x16x32_bf16(a1h, b0l, acc[1], 0, 0, 0);
  }
  const int quad = lane >> 4;
  const int o = ob + fr;
  float bias = 0.f;
#pragma unroll
  for (int e = 0; e < 10; ++e) bias += en[e] * bpool[e * 64 + o];
#pragma unroll
  for (int i2 = 0; i2 < 2; ++i2)
#pragma unroll
    for (int r = 0; r < 4; ++r) {
      const int b = i2 * 16 + quad * 4 + r;
      float hc = tanhf(acc[i2][r] + bias);
      float rr = rbf[(long)n * 2048 + b * 64 + o];
      float xv = x[(long)b * 131072 + (long)n * 64 + o];
      out[(long)b * 131072 + (long)n * 64 + o] = rr * xv + (1.0f - rr) * hc;
    }
}

extern "C" void kernel_launch(void* const* d_in, const int* in_sizes, int n_in,
                              void* d_out, int out_size, void* d_ws, size_t ws_size,
                              hipStream_t stream) {
  (void)in_sizes; (void)n_in; (void)out_size;
  const float* x   = (const float*)d_in[0];
  const float* emb = (const float*)d_in[2];
  const float* gwp = (const float*)d_in[3];
  const float* gbp = (const float*)d_in[4];
  const float* uwp = (const float*)d_in[5];
  const float* ubp = (const float*)d_in[6];
  float* out = (float*)d_out;
  char* ws = (char*)d_ws;

  // high-water 169,869,312 B (< round-1-proven 202,309,632). Guard:
  if (ws_size < 169869312ull) return;

  bf16_t* adjH = (bf16_t*)(ws);                  //  8 MiB
  bf16_t* adjL = (bf16_t*)(ws + 8388608);        //  8 MiB
  float*  Cnf  = (float*)(ws + 16777216);        // 32 MiB
  float*  Cg1f = (float*)(ws + 50331648);        // 32 MiB
  float*  Cg2f = (float*)(ws + 83886080);        // 32 MiB
  float*  rbf  = (float*)(ws + 117440512);       // 16 MiB
  float*  Pg   = (float*)(ws + 134217728);       // ~1 MiB
  float*  Pu   = (float*)(ws + 135266304);       // ~1 MiB
  char*   T    = ws + 136314880;                 // 32 MiB scratch
  // overlays
  float*  Xg1f = Cg1f;                           // fp32 2048x2048, dead after gate
  float*  Xg2f = Cg2f;                           // fp32 2048x2048, dead after gate
  bf16_t* XTh   = (bf16_t*)T;                    // 8 MiB
  bf16_t* XTl   = (bf16_t*)(T + 8388608);
  bf16_t* Xg1Th = (bf16_t*)(T + 16777216);
  bf16_t* Xg1Tl = (bf16_t*)(T + 25165824);
  bf16_t* CTh   = (bf16_t*)T;                    // 16 MiB (XT* dead)
  bf16_t* CTl   = (bf16_t*)(T + 16777216);
  bf16_t* Cg1Th = (bf16_t*)T;                    // 16 MiB (CT* dead)
  bf16_t* Cg1Tl = (bf16_t*)(T + 16777216);

  permute_pool<<<960, 256, 0, stream>>>(gwp, Pg, 192, 64, 128);
  permute_pool<<<960, 256, 0, stream>>>(uwp, Pu, 384, 128, 64);
  adj_softmax<<<2048, 256, 0, stream>>>(emb, adjH, adjL);
  split_xt<<<dim3(32, 32), 256, 0, stream>>>(x, XTh, XTl);
  cnf_x<<<2048, 256, 0, stream>>>(x, Cnf);

  // Xg1 = A@x (2-prod) ; Xg2 = 2*A@Xg1 - x (3-prod)
  fgemm<0, 1, 0><<<dim3(16, 16), 256, 0, stream>>>(adjH, nullptr, XTh, XTl, Xg1f,
                                                   2048, 2048, nullptr, nullptr);
  tsplit<<<dim3(32, 32), 256, 0, stream>>>(Xg1f, Xg1Th, Xg1Tl, 2048, 2048);
  fgemm<1, 1, 1><<<dim3(16, 16), 256, 0, stream>>>(adjH, adjL, Xg1Th, Xg1Tl, Xg2f,
                                                   2048, 2048, x, nullptr);

  gate_kernel<<<2048, 256, 0, stream>>>(x, Xg1f, Xg2f, Pg, gbp, emb, Cnf, rbf);

  // Cg1 = A@c (2-prod) ; Cg2 = 2*A@Cg1 - c (3-prod)
  tsplit<<<dim3(64, 32), 256, 0, stream>>>(Cnf, CTh, CTl, 2048, 4096);
  fgemm<0, 1, 0><<<dim3(32, 16), 256, 0, stream>>>(adjH, nullptr, CTh, CTl, Cg1f,
                                                   2048, 4096, nullptr, nullptr);
  tsplit<<<dim3(64, 32), 256, 0, stream>>>(Cg1f, Cg1Th, Cg1Tl, 2048, 4096);
  fgemm<1, 1, 2><<<dim3(32, 16), 256, 0, stream>>>(adjH, adjL, Cg1Th, Cg1Tl, Cg2f,
                                                   2048, 4096, nullptr, Cnf);

  update_kernel<<<2048, 256, 0, stream>>>(x, Cnf, Cg1f, Cg2f, Pu, ubp, emb, rbf, out);
}

// Round 5
// 685.289 us; speedup vs baseline: 1.1138x; 1.1138x over previous
//
#include <hip/hip_runtime.h>
#include <hip/hip_bf16.h>

typedef __hip_bfloat16 bf16_t;
typedef float f32x4 __attribute__((ext_vector_type(4)));
typedef __bf16 bf16x8 __attribute__((ext_vector_type(8)));

#define AS1 __attribute__((address_space(1)))
#define AS3 __attribute__((address_space(3)))

__device__ __forceinline__ void gload_lds16(const void* g, void* l) {
  __builtin_amdgcn_global_load_lds((const AS1 void*)g, (AS3 void*)l, 16, 0, 0);
}

__device__ __forceinline__ bf16_t f2b(float v) { return __float2bfloat16(v); }
__device__ __forceinline__ float b2f(bf16_t v) { return __bfloat162float(v); }

// ------------- adj = softmax(relu(E E^T), axis=1), hi/lo bf16 planes -------
__global__ __launch_bounds__(256) void adj_softmax(const float* __restrict__ emb,
                                                   bf16_t* __restrict__ adjH,
                                                   bf16_t* __restrict__ adjL) {
  __shared__ float vals[2048];
  __shared__ float red[16];
  const int n = blockIdx.x;
  const int t = threadIdx.x;
  const int lane = t & 63, wave = t >> 6;
  float en[10];
#pragma unroll
  for (int e = 0; e < 10; ++e) en[e] = emb[n * 10 + e];
  float lm = 0.0f;
  for (int m = t; m < 2048; m += 256) {
    const float* em = emb + m * 10;
    float d = 0.f;
#pragma unroll
    for (int e = 0; e < 10; ++e) d += en[e] * em[e];
    d = fmaxf(d, 0.0f);
    vals[m] = d;
    lm = fmaxf(lm, d);
  }
#pragma unroll
  for (int off = 32; off > 0; off >>= 1) lm = fmaxf(lm, __shfl_down(lm, off));
  if (lane == 0) red[wave] = lm;
  __syncthreads();
  const float gmax = fmaxf(fmaxf(red[0], red[1]), fmaxf(red[2], red[3]));
  float ls = 0.f;
  for (int m = t; m < 2048; m += 256) {
    float ev = expf(vals[m] - gmax);
    vals[m] = ev;
    ls += ev;
  }
#pragma unroll
  for (int off = 32; off > 0; off >>= 1) ls += __shfl_down(ls, off);
  if (lane == 0) red[8 + wave] = ls;
  __syncthreads();
  const float inv = 1.0f / (red[8] + red[9] + red[10] + red[11]);
  for (int m = t; m < 2048; m += 256) {
    float v = vals[m] * inv;
    bf16_t h = f2b(v);
    adjH[(long)n * 2048 + m] = h;
    adjL[(long)n * 2048 + m] = f2b(v - b2f(h));
  }
}

// ------------- XT[b*64+i][m] = x[b][m][i], hi/lo planes --------------------
__global__ __launch_bounds__(256) void split_xt(const float* __restrict__ x,
                                                bf16_t* __restrict__ XTh,
                                                bf16_t* __restrict__ XTl) {
  __shared__ float tile[64][65];
  const int m0 = blockIdx.x * 64;
  const int b = blockIdx.y;
  const int tx = threadIdx.x & 63, ty = threadIdx.x >> 6;
  for (int r = ty; r < 64; r += 4)
    tile[r][tx] = x[(long)b * 131072 + (long)(m0 + r) * 64 + tx];
  __syncthreads();
  for (int r = ty; r < 64; r += 4) {
    float v = tile[tx][r];
    bf16_t h = f2b(v);
    long idx = (long)(b * 64 + r) * 2048 + m0 + tx;
    XTh[idx] = h;
    XTl[idx] = f2b(v - b2f(h));
  }
}

// ------------- generic fp32 transpose-split: out[c][r] = in[r][c] ----------
__global__ __launch_bounds__(256) void tsplit(const float* __restrict__ in,
                                              bf16_t* __restrict__ oH,
                                              bf16_t* __restrict__ oL, int R, int C) {
  __shared__ float tile[64][65];
  const int c0 = blockIdx.x * 64, r0 = blockIdx.y * 64;
  const int tx = threadIdx.x & 63, ty = threadIdx.x >> 6;
  for (int r = ty; r < 64; r += 4)
    tile[r][tx] = in[(long)(r0 + r) * C + c0 + tx];
  __syncthreads();
  for (int r = ty; r < 64; r += 4) {
    float v = tile[tx][r];
    bf16_t h = f2b(v);
    long idx = (long)(c0 + r) * R + r0 + tx;
    oH[idx] = h;
    oL[idx] = f2b(v - b2f(h));
  }
}

// ------------- permute w_pool (E,3,I,O) -> P[e][o*KI + k*I+i], fp32 --------
__global__ __launch_bounds__(256) void permute_pool(const float* __restrict__ wp,
                                                    float* __restrict__ P,
                                                    int KI, int I, int O) {
  const int g = blockIdx.x * 256 + threadIdx.x;
  const int per = KI * O;  // 24576
  const int e = g / per, rem = g % per;
  const int o = rem / KI, kk = rem % KI;
  const int k = kk / I, i = kk % I;
  P[g] = wp[(long)((e * 3 + k) * I + i) * O + o];
}

// ------------- fused multi-product GEMM: C[i,j] = sum_k A[i,k]*B[j,k] ------
// products: Ah*Bh (+ Ah*Bl if BLO) (+ Al*Bh if ALO).  fp32 C.
// EPI 0: C=v   EPI 1: C=2v - x[b][gm][i] (gn=b*64+i)   EPI 2: C=2v - sub[gm*ldc+gn]
template <int ALO, int BLO, int EPI>
__global__ __launch_bounds__(256) void fgemm(const bf16_t* __restrict__ Ah,
                                             const bf16_t* __restrict__ Al,
                                             const bf16_t* __restrict__ Bh,
                                             const bf16_t* __restrict__ Bl,
                                             float* __restrict__ Cf, int K, int ldc,
                                             const float* __restrict__ xsrc,
                                             const float* __restrict__ sub) {
  __shared__ __align__(16) bf16_t Ash[128 * 32];
  __shared__ __align__(16) bf16_t Asl[128 * 32];
  __shared__ __align__(16) bf16_t Bsh[128 * 32];
  __shared__ __align__(16) bf16_t Bsl[128 * 32];
  const int t = threadIdx.x;
  const int wave = t >> 6, lane = t & 63;
  const long m0 = (long)blockIdx.y * 128;
  const long n0 = (long)blockIdx.x * 128;
  const int srow = t >> 2;
  const int skb = (t & 3) * 8;
  const long soff = (m0 + srow) * K + skb;
  const long soffB = (n0 + srow) * K + skb;
  const int wm = (wave >> 1) * 64;
  const int wn = (wave & 1) * 64;
  const int fr = lane & 15, qk = (lane >> 4) * 8;
  char* lAh = (char*)Ash + wave * 1024;
  char* lAl = (char*)Asl + wave * 1024;
  char* lBh = (char*)Bsh + wave * 1024;
  char* lBl = (char*)Bsl + wave * 1024;
  f32x4 acc[4][4] = {};
  for (int k0 = 0; k0 < K; k0 += 32) {
    gload_lds16(Ah + soff + k0, lAh);
    gload_lds16(Ah + soff + (long)64 * K + k0, lAh + 4096);
    gload_lds16(Bh + soffB + k0, lBh);
    gload_lds16(Bh + soffB + (long)64 * K + k0, lBh + 4096);
    if (ALO) {
      gload_lds16(Al + soff + k0, lAl);
      gload_lds16(Al + soff + (long)64 * K + k0, lAl + 4096);
    }
    if (BLO) {
      gload_lds16(Bl + soffB + k0, lBl);
      gload_lds16(Bl + soffB + (long)64 * K + k0, lBl + 4096);
    }
    __syncthreads();
    bf16x8 afh[4], bvh[4];
#pragma unroll
    for (int i = 0; i < 4; ++i) {
      afh[i] = *(const bf16x8*)(Ash + (wm + i * 16 + fr) * 32 + qk);
      bvh[i] = *(const bf16x8*)(Bsh + (wn + i * 16 + fr) * 32 + qk);
    }
#pragma unroll
    for (int i = 0; i < 4; ++i)
#pragma unroll
      for (int j = 0; j < 4; ++j)
        acc[i][j] = __builtin_amdgcn_mfma_f32_16x16x32_bf16(afh[i], bvh[j], acc[i][j], 0, 0, 0);
    if (BLO) {
      bf16x8 bvl[4];
#pragma unroll
      for (int j = 0; j < 4; ++j)
        bvl[j] = *(const bf16x8*)(Bsl + (wn + j * 16 + fr) * 32 + qk);
#pragma unroll
      for (int i = 0; i < 4; ++i)
#pragma unroll
        for (int j = 0; j < 4; ++j)
          acc[i][j] = __builtin_amdgcn_mfma_f32_16x16x32_bf16(afh[i], bvl[j], acc[i][j], 0, 0, 0);
    }
    if (ALO) {
      bf16x8 afl[4];
#pragma unroll
      for (int i = 0; i < 4; ++i)
        afl[i] = *(const bf16x8*)(Asl + (wm + i * 16 + fr) * 32 + qk);
#pragma unroll
      for (int i = 0; i < 4; ++i)
#pragma unroll
        for (int j = 0; j < 4; ++j)
          acc[i][j] = __builtin_amdgcn_mfma_f32_16x16x32_bf16(afl[i], bvh[j], acc[i][j], 0, 0, 0);
    }
    __syncthreads();
  }
  const int crow = (lane >> 4) * 4, ccol = lane & 15;
#pragma unroll
  for (int i = 0; i < 4; ++i)
#pragma unroll
    for (int j = 0; j < 4; ++j)
#pragma unroll
      for (int r = 0; r < 4; ++r) {
        long gm = m0 + wm + i * 16 + crow + r;
        long gn = n0 + wn + j * 16 + ccol;
        float v = acc[i][j][r];
        if (EPI == 0) Cf[gm * ldc + gn] = v;
        if (EPI == 1)
          Cf[gm * ldc + gn] =
              2.0f * v - xsrc[(long)(gn >> 6) * 131072 + gm * 64 + (gn & 63)];
        if (EPI == 2) Cf[gm * ldc + gn] = 2.0f * v - sub[gm * ldc + gn];
      }
}

// ------------- gate: (32x192)@W_n(192x128)+bias, sigmoid -------------------
// A = [x | Xg1 | Xg2] fp32 -> hi/lo.  W_n hi-only, generated in-kernel.
// z -> Zf[n][b*64+i] (fp32), r -> rbf (fp32).  LDS 76.8 KB -> 2 blocks/CU.
__global__ __launch_bounds__(256) void gate_kernel(
    const float* __restrict__ x, const float* __restrict__ Xg1f,
    const float* __restrict__ Xg2f, const float* __restrict__ P,
    const float* __restrict__ bpool, const float* __restrict__ emb,
    float* __restrict__ Zf, float* __restrict__ rbf) {
  __shared__ __align__(16) bf16_t Ahi[32 * 200];
  __shared__ __align__(16) bf16_t Alo[32 * 200];
  __shared__ __align__(16) bf16_t Whi[128 * 200];
  const int n = blockIdx.x;
  const int t = threadIdx.x;
  float en[10];
#pragma unroll
  for (int e = 0; e < 10; ++e) en[e] = emb[n * 10 + e];
  // ---- stage A (hi/lo) ----
  {
    const int b = t >> 3, i8 = (t & 7) * 8;
    const float* s[3];
    s[0] = x + (long)b * 131072 + (long)n * 64 + i8;
    s[1] = Xg1f + (long)n * 2048 + b * 64 + i8;
    s[2] = Xg2f + (long)n * 2048 + b * 64 + i8;
#pragma unroll
    for (int sec = 0; sec < 3; ++sec) {
      union { uint4 u; bf16_t h[8]; } th, tl;
#pragma unroll
      for (int j = 0; j < 8; ++j) {
        float v = s[sec][j];
        bf16_t h = f2b(v);
        th.h[j] = h;
        tl.h[j] = f2b(v - b2f(h));
      }
      *(uint4*)(Ahi + b * 200 + sec * 64 + i8) = th.u;
      *(uint4*)(Alo + b * 200 + sec * 64 + i8) = tl.u;
    }
  }
  // ---- generate W_n hi = bf16(sum_e en[e] * P[e][:]) ----
#pragma unroll
  for (int r = 0; r < 12; ++r) {
    const int c = r * 2048 + t * 8;
    float v[8] = {0, 0, 0, 0, 0, 0, 0, 0};
#pragma unroll
    for (int e = 0; e < 10; ++e) {
      const float4 p0 = *(const float4*)(P + (long)e * 24576 + c);
      const float4 p1 = *(const float4*)(P + (long)e * 24576 + c + 4);
      v[0] += en[e] * p0.x; v[1] += en[e] * p0.y;
      v[2] += en[e] * p0.z; v[3] += en[e] * p0.w;
      v[4] += en[e] * p1.x; v[5] += en[e] * p1.y;
      v[6] += en[e] * p1.z; v[7] += en[e] * p1.w;
    }
    const int o = c / 192, kk = c % 192;
    union { uint4 u; bf16_t h[8]; } th;
#pragma unroll
    for (int j = 0; j < 8; ++j) th.h[j] = f2b(v[j]);
    *(uint4*)(Whi + o * 200 + kk) = th.u;
  }
  __syncthreads();
  const int wave = t >> 6, lane = t & 63;
  const int ob = wave * 32;
  const int fr = lane & 15, qk = (lane >> 4) * 8;
  f32x4 acc[2][2] = {};
#pragma unroll
  for (int k0 = 0; k0 < 192; k0 += 32) {
    bf16x8 a0h = *(const bf16x8*)(Ahi + fr * 200 + k0 + qk);
    bf16x8 a1h = *(const bf16x8*)(Ahi + (16 + fr) * 200 + k0 + qk);
    bf16x8 a0l = *(const bf16x8*)(Alo + fr * 200 + k0 + qk);
    bf16x8 a1l = *(const bf16x8*)(Alo + (16 + fr) * 200 + k0 + qk);
    bf16x8 b0h = *(const bf16x8*)(Whi + (ob + fr) * 200 + k0 + qk);
    bf16x8 b1h = *(const bf16x8*)(Whi + (ob + 16 + fr) * 200 + k0 + qk);
    acc[0][0] = __builtin_amdgcn_mfma_f32_16x16x32_bf16(a0h, b0h, acc[0][0], 0, 0, 0);
    acc[0][0] = __builtin_amdgcn_mfma_f32_16x16x32_bf16(a0l, b0h, acc[0][0], 0, 0, 0);
    acc[1][0] = __builtin_amdgcn_mfma_f32_16x16x32_bf16(a1h, b0h, acc[1][0], 0, 0, 0);
    acc[1][0] = __builtin_amdgcn_mfma_f32_16x16x32_bf16(a1l, b0h, acc[1][0], 0, 0, 0);
    acc[0][1] = __builtin_amdgcn_mfma_f32_16x16x32_bf16(a0h, b1h, acc[0][1], 0, 0, 0);
    acc[0][1] = __builtin_amdgcn_mfma_f32_16x16x32_bf16(a0l, b1h, acc[0][1], 0, 0, 0);
    acc[1][1] = __builtin_amdgcn_mfma_f32_16x16x32_bf16(a1h, b1h, acc[1][1], 0, 0, 0);
    acc[1][1] = __builtin_amdgcn_mfma_f32_16x16x32_bf16(a1l, b1h, acc[1][1], 0, 0, 0);
  }
  const int quad = lane >> 4;
#pragma unroll
  for (int j = 0; j < 2; ++j) {
    const int o = ob + j * 16 + fr;
    float bias = 0.f;
#pragma unroll
    for (int e = 0; e < 10; ++e) bias += en[e] * bpool[e * 128 + o];
#pragma unroll
    for (int i2 = 0; i2 < 2; ++i2)
#pragma unroll
      for (int r = 0; r < 4; ++r) {
        const int b = i2 * 16 + quad * 4 + r;
        float v = acc[i2][j][r] + bias;
        v = 1.0f / (1.0f + expf(-v));
        if (o < 64)
          Zf[(long)n * 2048 + b * 64 + o] = v;  // z
        else
          rbf[(long)n * 2048 + b * 64 + (o - 64)] = v;  // r
      }
  }
}

// ------------- update: (32x384)@W_n(384x64), tanh, GRU blend ---------------
// grid 4096: block = (node n, o-half oh).  A = [x|z | Xg1|Cgz1 | Xg2|Cgz2]
// fp32 -> hi/lo.  W hi-only (32 o rows).  LDS 73.5 KB -> 2 blocks/CU.
__global__ __launch_bounds__(256) void update_kernel(
    const float* __restrict__ x, const float* __restrict__ Zf,
    const float* __restrict__ Xg1f, const float* __restrict__ Cgz1f,
    const float* __restrict__ Xg2f, const float* __restrict__ Cgz2f,
    const float* __restrict__ P, const float* __restrict__ bpool,
    const float* __restrict__ emb, const float* __restrict__ rbf,
    float* __restrict__ out) {
  __shared__ __align__(16) bf16_t Ahi[32 * 392];
  __shared__ __align__(16) bf16_t Alo[32 * 392];
  __shared__ __align__(16) bf16_t Whi[32 * 392];
  const int n = blockIdx.x >> 1;
  const int oh = blockIdx.x & 1;
  const int t = threadIdx.x;
  float en[10];
#pragma unroll
  for (int e = 0; e < 10; ++e) en[e] = emb[n * 10 + e];
  // ---- stage A (hi/lo): K-sections [x|z], [Xg1|Cgz1], [Xg2|Cgz2] ----
#pragma unroll
  for (int r = 0; r < 2; ++r) {
    const int c = r * 2048 + t * 8;       // (b, j) over 32 x 128
    const int b = c >> 7, j = c & 127;
    const int lo64 = j & 63;
    const float* s[3];
    s[0] = (j < 64) ? (x + (long)b * 131072 + (long)n * 64 + lo64)
                    : (Zf + (long)n * 2048 + b * 64 + lo64);
    s[1] = (j < 64) ? (Xg1f + (long)n * 2048 + b * 64 + lo64)
                    : (Cgz1f + (long)n * 2048 + b * 64 + lo64);
    s[2] = (j < 64) ? (Xg2f + (long)n * 2048 + b * 64 + lo64)
                    : (Cgz2f + (long)n * 2048 + b * 64 + lo64);
#pragma unroll
    for (int sec = 0; sec < 3; ++sec) {
      union { uint4 u; bf16_t h[8]; } th, tl;
#pragma unroll
      for (int q = 0; q < 8; ++q) {
        float v = s[sec][q];
        bf16_t h = f2b(v);
        th.h[q] = h;
        tl.h[q] = f2b(v - b2f(h));
      }
      *(uint4*)(Ahi + b * 392 + sec * 128 + j) = th.u;
      *(uint4*)(Alo + b * 392 + sec * 128 + j) = tl.u;
    }
  }
  // ---- generate W hi for this o-half: 32 o x 384 k ----
  const float* Pb = P + (long)oh * 12288;
#pragma unroll
  for (int r = 0; r < 6; ++r) {
    const int c = r * 2048 + t * 8;       // 0..12288 over (o_loc*384 + kk)
    float v[8] = {0, 0, 0, 0, 0, 0, 0, 0};
#pragma unroll
    for (int e = 0; e < 10; ++e) {
      const float4 p0 = *(const float4*)(Pb + (long)e * 24576 + c);
      const float4 p1 = *(const float4*)(Pb + (long)e * 24576 + c + 4);
      v[0] += en[e] * p0.x; v[1] += en[e] * p0.y;
      v[2] += en[e] * p0.z; v[3] += en[e] * p0.w;
      v[4] += en[e] * p1.x; v[5] += en[e] * p1.y;
      v[6] += en[e] * p1.z; v[7] += en[e] * p1.w;
    }
    const int o = c / 384, kk = c % 384;
    union { uint4 u; bf16_t h[8]; } th;
#pragma unroll
    for (int j = 0; j < 8; ++j) th.h[j] = f2b(v[j]);
    *(uint4*)(Whi + o * 392 + kk) = th.u;
  }
  __syncthreads();
  const int wave = t >> 6, lane = t & 63;
  const int mh = (wave >> 1) * 16;        // m-tile (batch rows)
  const int ob = (wave & 1) * 16;         // o-tile within the 32-o half
  const int fr = lane & 15, qk = (lane >> 4) * 8;
  f32x4 acc = {};
#pragma unroll
  for (int k0 = 0; k0 < 384; k0 += 32) {
    bf16x8 ah = *(const bf16x8*)(Ahi + (mh + fr) * 392 + k0 + qk);
    bf16x8 al = *(const bf16x8*)(Alo + (mh + fr) * 392 + k0 + qk);
    bf16x8 bh = *(const bf16x8*)(Whi + (ob + fr) * 392 + k0 + qk);
    acc = __builtin_amdgcn_mfma_f32_16x16x32_bf16(ah, bh, acc, 0, 0, 0);
    acc = __builtin_amdgcn_mfma_f32_16x16x32_bf16(al, bh, acc, 0, 0, 0);
  }
  const int quad = lane >> 4;
  const int og = oh * 32 + ob + fr;
  float bias = 0.f;
#pragma unroll
  for (int e = 0; e < 10; ++e) bias += en[e] * bpool[e * 64 + og];
#pragma unroll
  for (int r = 0; r < 4; ++r) {
    const int b = mh + quad * 4 + r;
    float hc = tanhf(acc[r] + bias);
    float rr = rbf[(long)n * 2048 + b * 64 + og];
    float xv = x[(long)b * 131072 + (long)n * 64 + og];
    out[(long)b * 131072 + (long)n * 64 + og] = rr * xv + (1.0f - rr) * hc;
  }
}

extern "C" void kernel_launch(void* const* d_in, const int* in_sizes, int n_in,
                              void* d_out, int out_size, void* d_ws, size_t ws_size,
                              hipStream_t stream) {
  (void)in_sizes; (void)n_in; (void)out_size;
  const float* x   = (const float*)d_in[0];
  const float* emb = (const float*)d_in[2];
  const float* gwp = (const float*)d_in[3];
  const float* gbp = (const float*)d_in[4];
  const float* uwp = (const float*)d_in[5];
  const float* ubp = (const float*)d_in[6];
  float* out = (float*)d_out;
  char* ws = (char*)d_ws;

  if (ws_size < 169869312ull) return;  // proven-safe guard

  bf16_t* adjH  = (bf16_t*)(ws);                 //  8 MiB
  bf16_t* adjL  = (bf16_t*)(ws + 8388608);       //  8 MiB
  float*  Zf    = (float*)(ws + 16777216);       // 16 MiB  z[n][b*64+i]
  float*  Xg1f  = (float*)(ws + 33554432);       // 16 MiB
  float*  Xg2f  = (float*)(ws + 50331648);       // 16 MiB
  float*  Cgz1f = (float*)(ws + 67108864);       // 16 MiB
  float*  Cgz2f = (float*)(ws + 83886080);       // 16 MiB
  float*  rbf   = (float*)(ws + 100663296);      // 16 MiB
  float*  Pg    = (float*)(ws + 117440512);      // 983040 B
  float*  Pu    = (float*)(ws + 118423552);      // 983040 B
  char*   T     = ws + 119406592;                // 32 MiB scratch
  // T overlays (phase1: X path, phase2: z path)
  bf16_t* XTh    = (bf16_t*)T;
  bf16_t* XTl    = (bf16_t*)(T + 8388608);
  bf16_t* Xg1Th  = (bf16_t*)(T + 16777216);
  bf16_t* Xg1Tl  = (bf16_t*)(T + 25165824);
  bf16_t* zTh    = (bf16_t*)T;                   // XT* dead
  bf16_t* zTl    = (bf16_t*)(T + 8388608);
  bf16_t* Cgz1Th = (bf16_t*)(T + 16777216);      // Xg1T* dead
  bf16_t* Cgz1Tl = (bf16_t*)(T + 25165824);

  permute_pool<<<960, 256, 0, stream>>>(gwp, Pg, 192, 64, 128);
  permute_pool<<<960, 256, 0, stream>>>(uwp, Pu, 384, 128, 64);
  adj_softmax<<<2048, 256, 0, stream>>>(emb, adjH, adjL);
  split_xt<<<dim3(32, 32), 256, 0, stream>>>(x, XTh, XTl);

  // Xg1 = A@x (2-prod) ; Xg2 = 2*A@Xg1 - x (3-prod)
  fgemm<0, 1, 0><<<dim3(16, 16), 256, 0, stream>>>(adjH, nullptr, XTh, XTl, Xg1f,
                                                   2048, 2048, nullptr, nullptr);
  tsplit<<<dim3(32, 32), 256, 0, stream>>>(Xg1f, Xg1Th, Xg1Tl, 2048, 2048);
  fgemm<1, 1, 1><<<dim3(16, 16), 256, 0, stream>>>(adjH, adjL, Xg1Th, Xg1Tl, Xg2f,
                                                   2048, 2048, x, nullptr);

  gate_kernel<<<2048, 256, 0, stream>>>(x, Xg1f, Xg2f, Pg, gbp, emb, Zf, rbf);

  // z-half of the candidate chain only (x-half == Xg1/Xg2, reused):
  // Cgz1 = A@z (2-prod) ; Cgz2 = 2*A@Cgz1 - z (3-prod)
  tsplit<<<dim3(32, 32), 256, 0, stream>>>(Zf, zTh, zTl, 2048, 2048);
  fgemm<0, 1, 0><<<dim3(16, 16), 256, 0, stream>>>(adjH, nullptr, zTh, zTl, Cgz1f,
                                                   2048, 2048, nullptr, nullptr);
  tsplit<<<dim3(32, 32), 256, 0, stream>>>(Cgz1f, Cgz1Th, Cgz1Tl, 2048, 2048);
  fgemm<1, 1, 2><<<dim3(16, 16), 256, 0, stream>>>(adjH, adjL, Cgz1Th, Cgz1Tl, Cgz2f,
                                                   2048, 2048, nullptr, Zf);

  update_kernel<<<4096, 256, 0, stream>>>(x, Zf, Xg1f, Cgz1f, Xg2f, Cgz2f, Pu,
                                          ubp, emb, rbf, out);
}

// Round 6
// 588.813 us; speedup vs baseline: 1.2963x; 1.1638x over previous
//
#include <hip/hip_runtime.h>
#include <hip/hip_bf16.h>

typedef __hip_bfloat16 bf16_t;
typedef float f32x4 __attribute__((ext_vector_type(4)));
typedef __bf16 bf16x8 __attribute__((ext_vector_type(8)));

#define AS1 __attribute__((address_space(1)))
#define AS3 __attribute__((address_space(3)))

__device__ __forceinline__ void gload_lds16(const void* g, void* l) {
  __builtin_amdgcn_global_load_lds((const AS1 void*)g, (AS3 void*)l, 16, 0, 0);
}

__device__ __forceinline__ bf16_t f2b(float v) { return __float2bfloat16(v); }
__device__ __forceinline__ float b2f(bf16_t v) { return __bfloat162float(v); }

// ------------- adj = softmax(relu(E E^T), axis=1), hi/lo bf16 planes -------
__global__ __launch_bounds__(256) void adj_softmax(const float* __restrict__ emb,
                                                   bf16_t* __restrict__ adjH,
                                                   bf16_t* __restrict__ adjL) {
  __shared__ float vals[2048];
  __shared__ float red[16];
  const int n = blockIdx.x;
  const int t = threadIdx.x;
  const int lane = t & 63, wave = t >> 6;
  float en[10];
#pragma unroll
  for (int e = 0; e < 10; ++e) en[e] = emb[n * 10 + e];
  float lm = 0.0f;
  for (int m = t; m < 2048; m += 256) {
    const float* em = emb + m * 10;
    float d = 0.f;
#pragma unroll
    for (int e = 0; e < 10; ++e) d += en[e] * em[e];
    d = fmaxf(d, 0.0f);
    vals[m] = d;
    lm = fmaxf(lm, d);
  }
#pragma unroll
  for (int off = 32; off > 0; off >>= 1) lm = fmaxf(lm, __shfl_down(lm, off));
  if (lane == 0) red[wave] = lm;
  __syncthreads();
  const float gmax = fmaxf(fmaxf(red[0], red[1]), fmaxf(red[2], red[3]));
  float ls = 0.f;
  for (int m = t; m < 2048; m += 256) {
    float ev = expf(vals[m] - gmax);
    vals[m] = ev;
    ls += ev;
  }
#pragma unroll
  for (int off = 32; off > 0; off >>= 1) ls += __shfl_down(ls, off);
  if (lane == 0) red[8 + wave] = ls;
  __syncthreads();
  const float inv = 1.0f / (red[8] + red[9] + red[10] + red[11]);
  for (int m = t; m < 2048; m += 256) {
    float v = vals[m] * inv;
    bf16_t h = f2b(v);
    adjH[(long)n * 2048 + m] = h;
    adjL[(long)n * 2048 + m] = f2b(v - b2f(h));
  }
}

// ------------- XT[b*64+i][m] = x[b][m][i], hi/lo planes --------------------
__global__ __launch_bounds__(256) void split_xt(const float* __restrict__ x,
                                                bf16_t* __restrict__ XTh,
                                                bf16_t* __restrict__ XTl) {
  __shared__ float tile[64][65];
  const int m0 = blockIdx.x * 64;
  const int b = blockIdx.y;
  const int tx = threadIdx.x & 63, ty = threadIdx.x >> 6;
  for (int r = ty; r < 64; r += 4)
    tile[r][tx] = x[(long)b * 131072 + (long)(m0 + r) * 64 + tx];
  __syncthreads();
  for (int r = ty; r < 64; r += 4) {
    float v = tile[tx][r];
    bf16_t h = f2b(v);
    long idx = (long)(b * 64 + r) * 2048 + m0 + tx;
    XTh[idx] = h;
    XTl[idx] = f2b(v - b2f(h));
  }
}

// ------------- generic fp32 transpose-split: out[c][r] = in[r][c] ----------
__global__ __launch_bounds__(256) void tsplit(const float* __restrict__ in,
                                              bf16_t* __restrict__ oH,
                                              bf16_t* __restrict__ oL, int R, int C) {
  __shared__ float tile[64][65];
  const int c0 = blockIdx.x * 64, r0 = blockIdx.y * 64;
  const int tx = threadIdx.x & 63, ty = threadIdx.x >> 6;
  for (int r = ty; r < 64; r += 4)
    tile[r][tx] = in[(long)(r0 + r) * C + c0 + tx];
  __syncthreads();
  for (int r = ty; r < 64; r += 4) {
    float v = tile[tx][r];
    bf16_t h = f2b(v);
    long idx = (long)(c0 + r) * R + r0 + tx;
    oH[idx] = h;
    oL[idx] = f2b(v - b2f(h));
  }
}

// ------------- permute w_pool (E,3,I,O) -> P[e][o*KI + k*I+i], fp32 --------
__global__ __launch_bounds__(256) void permute_pool(const float* __restrict__ wp,
                                                    float* __restrict__ P,
                                                    int KI, int I, int O) {
  const int g = blockIdx.x * 256 + threadIdx.x;
  const int per = KI * O;  // 24576
  const int e = g / per, rem = g % per;
  const int o = rem / KI, kk = rem % KI;
  const int k = kk / I, i = kk % I;
  P[g] = wp[(long)((e * 3 + k) * I + i) * O + o];
}

// ------------- W[n][c] = bf16(sum_e emb[n,e] * P[e][c]) --------------------
__global__ __launch_bounds__(256) void wgen(const float* __restrict__ P,
                                            const float* __restrict__ emb,
                                            bf16_t* __restrict__ W) {
  __shared__ float Ps[10 * 1024];
  __shared__ float es[160];
  const int c0 = blockIdx.x * 1024;
  const int n0 = blockIdx.y * 16;
  const int t = threadIdx.x;
  for (int g = t; g < 10240; g += 256) {
    int e = g >> 10, idx = g & 1023;
    Ps[g] = P[(long)e * 24576 + c0 + idx];
  }
  if (t < 160) es[t] = emb[n0 * 10 + t];
  __syncthreads();
  for (int nn = 0; nn < 16; ++nn) {
    float e0 = es[nn * 10 + 0], e1 = es[nn * 10 + 1], e2 = es[nn * 10 + 2],
          e3 = es[nn * 10 + 3], e4 = es[nn * 10 + 4], e5 = es[nn * 10 + 5],
          e6 = es[nn * 10 + 6], e7 = es[nn * 10 + 7], e8 = es[nn * 10 + 8],
          e9 = es[nn * 10 + 9];
#pragma unroll
    for (int q = 0; q < 4; ++q) {
      int idx = q * 256 + t;
      float v = e0 * Ps[idx] + e1 * Ps[1024 + idx] + e2 * Ps[2048 + idx] +
                e3 * Ps[3072 + idx] + e4 * Ps[4096 + idx] + e5 * Ps[5120 + idx] +
                e6 * Ps[6144 + idx] + e7 * Ps[7168 + idx] + e8 * Ps[8192 + idx] +
                e9 * Ps[9216 + idx];
      W[(long)(n0 + nn) * 24576 + c0 + idx] = f2b(v);
    }
  }
}

// ------------- fused multi-product GEMM (128x64 tile, raw fp32 out) --------
// C[i,j] = sum_k A[i,k]*B[j,k]; products Ah*Bh (+Ah*Bl if BLO) (+Al*Bh if ALO)
// grid (N/64, M/128), 256 threads.
template <int ALO, int BLO>
__global__ __launch_bounds__(256) void fgemm(const bf16_t* __restrict__ Ah,
                                             const bf16_t* __restrict__ Al,
                                             const bf16_t* __restrict__ Bh,
                                             const bf16_t* __restrict__ Bl,
                                             float* __restrict__ Cf, int K, int ldc) {
  __shared__ __align__(16) bf16_t Ash[128 * 32];
  __shared__ __align__(16) bf16_t Asl[128 * 32];
  __shared__ __align__(16) bf16_t Bsh[64 * 32];
  __shared__ __align__(16) bf16_t Bsl[64 * 32];
  const int t = threadIdx.x;
  const int wave = t >> 6, lane = t & 63;
  const long m0 = (long)blockIdx.y * 128;
  const long n0 = (long)blockIdx.x * 64;
  const int srow = t >> 2;
  const int skb = (t & 3) * 8;
  const long aoff = (m0 + srow) * K + skb;
  const long boff = (n0 + srow) * K + skb;
  const int wm = wave * 32;
  const int fr = lane & 15, qk = (lane >> 4) * 8;
  char* lAh = (char*)Ash + wave * 1024;
  char* lAl = (char*)Asl + wave * 1024;
  char* lBh = (char*)Bsh + wave * 1024;
  char* lBl = (char*)Bsl + wave * 1024;
  f32x4 acc[2][4] = {};
  for (int k0 = 0; k0 < K; k0 += 32) {
    gload_lds16(Ah + aoff + k0, lAh);
    gload_lds16(Ah + aoff + (long)64 * K + k0, lAh + 4096);
    gload_lds16(Bh + boff + k0, lBh);
    if (ALO) {
      gload_lds16(Al + aoff + k0, lAl);
      gload_lds16(Al + aoff + (long)64 * K + k0, lAl + 4096);
    }
    if (BLO) gload_lds16(Bl + boff + k0, lBl);
    __syncthreads();
    bf16x8 ah[2], bh[4];
#pragma unroll
    for (int i = 0; i < 2; ++i)
      ah[i] = *(const bf16x8*)(Ash + (wm + i * 16 + fr) * 32 + qk);
#pragma unroll
    for (int j = 0; j < 4; ++j)
      bh[j] = *(const bf16x8*)(Bsh + (j * 16 + fr) * 32 + qk);
#pragma unroll
    for (int i = 0; i < 2; ++i)
#pragma unroll
      for (int j = 0; j < 4; ++j)
        acc[i][j] = __builtin_amdgcn_mfma_f32_16x16x32_bf16(ah[i], bh[j], acc[i][j], 0, 0, 0);
    if (BLO) {
      bf16x8 bl[4];
#pragma unroll
      for (int j = 0; j < 4; ++j)
        bl[j] = *(const bf16x8*)(Bsl + (j * 16 + fr) * 32 + qk);
#pragma unroll
      for (int i = 0; i < 2; ++i)
#pragma unroll
        for (int j = 0; j < 4; ++j)
          acc[i][j] = __builtin_amdgcn_mfma_f32_16x16x32_bf16(ah[i], bl[j], acc[i][j], 0, 0, 0);
    }
    if (ALO) {
      bf16x8 al[2];
#pragma unroll
      for (int i = 0; i < 2; ++i)
        al[i] = *(const bf16x8*)(Asl + (wm + i * 16 + fr) * 32 + qk);
#pragma unroll
      for (int i = 0; i < 2; ++i)
#pragma unroll
        for (int j = 0; j < 4; ++j)
          acc[i][j] = __builtin_amdgcn_mfma_f32_16x16x32_bf16(al[i], bh[j], acc[i][j], 0, 0, 0);
    }
    __syncthreads();
  }
  const int crow = (lane >> 4) * 4, ccol = lane & 15;
#pragma unroll
  for (int i = 0; i < 2; ++i)
#pragma unroll
    for (int j = 0; j < 4; ++j)
#pragma unroll
      for (int r = 0; r < 4; ++r) {
        long gm = m0 + wm + i * 16 + crow + r;
        long gn = n0 + j * 16 + ccol;
        Cf[gm * ldc + gn] = acc[i][j][r];
      }
}

// ------------- gate (o-split): (32x192)@W_half(192x64)+bias, sigmoid -------
// grid 4096: block = (n, oh).  A = [x | Xg1 | 2*Xg2raw - x] fp32 -> hi/lo.
// W half generated in-kernel from Pg slice.  oh=0 -> Zf, oh=1 -> rb (bf16).
__global__ __launch_bounds__(256) void gate_kernel(
    const float* __restrict__ x, const float* __restrict__ Xg1f,
    const float* __restrict__ Xg2r, const float* __restrict__ P,
    const float* __restrict__ bpool, const float* __restrict__ emb,
    float* __restrict__ Zf, bf16_t* __restrict__ rb) {
  __shared__ __align__(16) bf16_t Ahi[32 * 200];
  __shared__ __align__(16) bf16_t Alo[32 * 200];
  __shared__ __align__(16) bf16_t Whi[64 * 200];
  const int n = blockIdx.x >> 1;
  const int oh = blockIdx.x & 1;
  const int t = threadIdx.x;
  float en[10];
#pragma unroll
  for (int e = 0; e < 10; ++e) en[e] = emb[n * 10 + e];
  // ---- stage A (hi/lo): sec0=x, sec1=Xg1, sec2=2*Xg2raw - x ----
  {
    const int b = t >> 3, i8 = (t & 7) * 8;
    const float* s0 = x + (long)b * 131072 + (long)n * 64 + i8;
    const float* s1 = Xg1f + (long)n * 2048 + b * 64 + i8;
    const float* s2 = Xg2r + (long)n * 2048 + b * 64 + i8;
    float v0[8], v1[8], v2[8];
#pragma unroll
    for (int j = 0; j < 8; ++j) v0[j] = s0[j];
#pragma unroll
    for (int j = 0; j < 8; ++j) v1[j] = s1[j];
#pragma unroll
    for (int j = 0; j < 8; ++j) v2[j] = 2.0f * s2[j] - v0[j];
    union { uint4 u; bf16_t h[8]; } th, tl;
#pragma unroll
    for (int j = 0; j < 8; ++j) {
      bf16_t h = f2b(v0[j]); th.h[j] = h; tl.h[j] = f2b(v0[j] - b2f(h));
    }
    *(uint4*)(Ahi + b * 200 + i8) = th.u;
    *(uint4*)(Alo + b * 200 + i8) = tl.u;
#pragma unroll
    for (int j = 0; j < 8; ++j) {
      bf16_t h = f2b(v1[j]); th.h[j] = h; tl.h[j] = f2b(v1[j] - b2f(h));
    }
    *(uint4*)(Ahi + b * 200 + 64 + i8) = th.u;
    *(uint4*)(Alo + b * 200 + 64 + i8) = tl.u;
#pragma unroll
    for (int j = 0; j < 8; ++j) {
      bf16_t h = f2b(v2[j]); th.h[j] = h; tl.h[j] = f2b(v2[j] - b2f(h));
    }
    *(uint4*)(Ahi + b * 200 + 128 + i8) = th.u;
    *(uint4*)(Alo + b * 200 + 128 + i8) = tl.u;
  }
  // ---- generate W half (64 o rows): Whi = bf16(sum_e en[e]*P[e][slice]) ----
  const float* Pb = P + (long)oh * 12288;
#pragma unroll
  for (int r = 0; r < 6; ++r) {
    const int c = r * 2048 + t * 8;  // 0..12287
    float v[8] = {0, 0, 0, 0, 0, 0, 0, 0};
#pragma unroll
    for (int e = 0; e < 10; ++e) {
      const float4 p0 = *(const float4*)(Pb + (long)e * 24576 + c);
      const float4 p1 = *(const float4*)(Pb + (long)e * 24576 + c + 4);
      v[0] += en[e] * p0.x; v[1] += en[e] * p0.y;
      v[2] += en[e] * p0.z; v[3] += en[e] * p0.w;
      v[4] += en[e] * p1.x; v[5] += en[e] * p1.y;
      v[6] += en[e] * p1.z; v[7] += en[e] * p1.w;
    }
    const int o = c / 192, kk = c % 192;
    union { uint4 u; bf16_t h[8]; } th;
#pragma unroll
    for (int j = 0; j < 8; ++j) th.h[j] = f2b(v[j]);
    *(uint4*)(Whi + o * 200 + kk) = th.u;
  }
  __syncthreads();
  const int wave = t >> 6, lane = t & 63;
  const int ob = wave * 16;
  const int fr = lane & 15, qk = (lane >> 4) * 8;
  f32x4 acc[2] = {};
#pragma unroll
  for (int k0 = 0; k0 < 192; k0 += 32) {
    bf16x8 a0h = *(const bf16x8*)(Ahi + fr * 200 + k0 + qk);
    bf16x8 a1h = *(const bf16x8*)(Ahi + (16 + fr) * 200 + k0 + qk);
    bf16x8 a0l = *(const bf16x8*)(Alo + fr * 200 + k0 + qk);
    bf16x8 a1l = *(const bf16x8*)(Alo + (16 + fr) * 200 + k0 + qk);
    bf16x8 bh = *(const bf16x8*)(Whi + (ob + fr) * 200 + k0 + qk);
    acc[0] = __builtin_amdgcn_mfma_f32_16x16x32_bf16(a0h, bh, acc[0], 0, 0, 0);
    acc[0] = __builtin_amdgcn_mfma_f32_16x16x32_bf16(a0l, bh, acc[0], 0, 0, 0);
    acc[1] = __builtin_amdgcn_mfma_f32_16x16x32_bf16(a1h, bh, acc[1], 0, 0, 0);
    acc[1] = __builtin_amdgcn_mfma_f32_16x16x32_bf16(a1l, bh, acc[1], 0, 0, 0);
  }
  const int quad = lane >> 4;
  const int o_loc = ob + fr;
  const int o_glob = oh * 64 + o_loc;
  float bias = 0.f;
#pragma unroll
  for (int e = 0; e < 10; ++e) bias += en[e] * bpool[e * 128 + o_glob];
#pragma unroll
  for (int i2 = 0; i2 < 2; ++i2)
#pragma unroll
    for (int r = 0; r < 4; ++r) {
      const int b = i2 * 16 + quad * 4 + r;
      float v = acc[i2][r] + bias;
      v = 1.0f / (1.0f + expf(-v));
      if (oh == 0)
        Zf[(long)n * 2048 + b * 64 + o_loc] = v;
      else
        rb[(long)n * 2048 + b * 64 + o_loc] = f2b(v);
    }
}

// ------------- update: (32x384)@W_half(384x32), tanh, GRU blend ------------
// grid 4096: block = (n, oh).  A = [x|z | Xg1|Cgz1 | 2*Xg2r-x | 2*Cgz2r-z]
// fp32 -> hi/lo.  W half loaded from materialized Wu (bf16).
__global__ __launch_bounds__(256) void update_kernel(
    const float* __restrict__ x, const float* __restrict__ Zf,
    const float* __restrict__ Xg1f, const float* __restrict__ Cgz1f,
    const float* __restrict__ Xg2r, const float* __restrict__ Cgz2r,
    const bf16_t* __restrict__ Wu, const float* __restrict__ bpool,
    const float* __restrict__ emb, const bf16_t* __restrict__ rb,
    float* __restrict__ out) {
  __shared__ __align__(16) bf16_t Ahi[32 * 392];
  __shared__ __align__(16) bf16_t Alo[32 * 392];
  __shared__ __align__(16) bf16_t Whi[32 * 392];
  const int n = blockIdx.x >> 1;
  const int oh = blockIdx.x & 1;
  const int t = threadIdx.x;
  float en[10];
#pragma unroll
  for (int e = 0; e < 10; ++e) en[e] = emb[n * 10 + e];
  // ---- stage A (hi/lo) ----
#pragma unroll
  for (int r = 0; r < 2; ++r) {
    const int c = r * 2048 + t * 8;  // (b, j) over 32 x 128
    const int b = c >> 7, j = c & 127;
    const int lo64 = j & 63;
    const float* s0 = (j < 64) ? (x + (long)b * 131072 + (long)n * 64 + lo64)
                               : (Zf + (long)n * 2048 + b * 64 + lo64);
    const float* s1 = (j < 64) ? (Xg1f + (long)n * 2048 + b * 64 + lo64)
                               : (Cgz1f + (long)n * 2048 + b * 64 + lo64);
    const float* s2 = (j < 64) ? (Xg2r + (long)n * 2048 + b * 64 + lo64)
                               : (Cgz2r + (long)n * 2048 + b * 64 + lo64);
    float v0[8], v1[8], v2[8];
#pragma unroll
    for (int q = 0; q < 8; ++q) v0[q] = s0[q];
#pragma unroll
    for (int q = 0; q < 8; ++q) v1[q] = s1[q];
#pragma unroll
    for (int q = 0; q < 8; ++q) v2[q] = 2.0f * s2[q] - v0[q];
    union { uint4 u; bf16_t h[8]; } th, tl;
#pragma unroll
    for (int q = 0; q < 8; ++q) {
      bf16_t h = f2b(v0[q]); th.h[q] = h; tl.h[q] = f2b(v0[q] - b2f(h));
    }
    *(uint4*)(Ahi + b * 392 + j) = th.u;
    *(uint4*)(Alo + b * 392 + j) = tl.u;
#pragma unroll
    for (int q = 0; q < 8; ++q) {
      bf16_t h = f2b(v1[q]); th.h[q] = h; tl.h[q] = f2b(v1[q] - b2f(h));
    }
    *(uint4*)(Ahi + b * 392 + 128 + j) = th.u;
    *(uint4*)(Alo + b * 392 + 128 + j) = tl.u;
#pragma unroll
    for (int q = 0; q < 8; ++q) {
      bf16_t h = f2b(v2[q]); th.h[q] = h; tl.h[q] = f2b(v2[q] - b2f(h));
    }
    *(uint4*)(Ahi + b * 392 + 256 + j) = th.u;
    *(uint4*)(Alo + b * 392 + 256 + j) = tl.u;
  }
  // ---- load W half (32 o rows x 384 k) from materialized Wu ----
  const bf16_t* Wp = Wu + (long)n * 24576 + (long)oh * 12288;
#pragma unroll
  for (int r = 0; r < 6; ++r) {
    const int g = r * 2048 + t * 8;  // 0..12287
    const int o = g / 384, kk = g % 384;
    *(uint4*)(Whi + o * 392 + kk) = *(const uint4*)(Wp + g);
  }
  __syncthreads();
  const int wave = t >> 6, lane = t & 63;
  const int mh = (wave >> 1) * 16;
  const int ob = (wave & 1) * 16;
  const int fr = lane & 15, qk = (lane >> 4) * 8;
  f32x4 acc = {};
#pragma unroll
  for (int k0 = 0; k0 < 384; k0 += 32) {
    bf16x8 ah = *(const bf16x8*)(Ahi + (mh + fr) * 392 + k0 + qk);
    bf16x8 al = *(const bf16x8*)(Alo + (mh + fr) * 392 + k0 + qk);
    bf16x8 bh = *(const bf16x8*)(Whi + (ob + fr) * 392 + k0 + qk);
    acc = __builtin_amdgcn_mfma_f32_16x16x32_bf16(ah, bh, acc, 0, 0, 0);
    acc = __builtin_amdgcn_mfma_f32_16x16x32_bf16(al, bh, acc, 0, 0, 0);
  }
  const int quad = lane >> 4;
  const int og = oh * 32 + ob + fr;
  float bias = 0.f;
#pragma unroll
  for (int e = 0; e < 10; ++e) bias += en[e] * bpool[e * 64 + og];
#pragma unroll
  for (int r = 0; r < 4; ++r) {
    const int b = mh + quad * 4 + r;
    float hc = tanhf(acc[r] + bias);
    float rr = b2f(rb[(long)n * 2048 + b * 64 + og]);
    float xv = x[(long)b * 131072 + (long)n * 64 + og];
    out[(long)b * 131072 + (long)n * 64 + og] = rr * xv + (1.0f - rr) * hc;
  }
}

extern "C" void kernel_launch(void* const* d_in, const int* in_sizes, int n_in,
                              void* d_out, int out_size, void* d_ws, size_t ws_size,
                              hipStream_t stream) {
  (void)in_sizes; (void)n_in; (void)out_size;
  const float* x   = (const float*)d_in[0];
  const float* emb = (const float*)d_in[2];
  const float* gwp = (const float*)d_in[3];
  const float* gbp = (const float*)d_in[4];
  const float* uwp = (const float*)d_in[5];
  const float* ubp = (const float*)d_in[6];
  float* out = (float*)d_out;
  char* ws = (char*)d_ws;

  // high-water 194,904,064 B (< round-1-proven 202,309,632). Guard:
  if (ws_size < 194904064ull) return;

  float*  Xg1f  = (float*)(ws);                  // 16 MiB [0, 16M)
  float*  Xg2r  = (float*)(ws + 16777216);       // 16 MiB raw A@Xg1
  float*  Zf    = (float*)(ws + 33554432);       // 16 MiB
  float*  Cgz1f = (float*)(ws + 50331648);       // 16 MiB
  float*  Cgz2r = (float*)(ws + 67108864);       // 16 MiB raw A@Cgz1
  bf16_t* rb    = (bf16_t*)(ws + 83886080);      //  8 MiB r gate (bf16)
  bf16_t* Wu    = (bf16_t*)(ws + 92274688);      // 100 MiB [92M..192M): update W
  // pre-wgen overlays inside the Wu region (all dead before wgen_u runs):
  bf16_t* adjH  = (bf16_t*)(ws + 92274688);      //  8 MiB
  bf16_t* adjL  = (bf16_t*)(ws + 100663296);     //  8 MiB
  char*   S     = ws + 109051904;                // 16 MiB transpose scratch
  float*  Pg    = (float*)(ws + 192937984);      // 983040 B (outside Wu)
  float*  Pu    = (float*)(ws + 193921024);      // 983040 B
  bf16_t* Sh    = (bf16_t*)S;                    // hi plane (8 MiB)
  bf16_t* Sl    = (bf16_t*)(S + 8388608);        // lo plane (8 MiB)

  permute_pool<<<960, 256, 0, stream>>>(gwp, Pg, 192, 64, 128);
  permute_pool<<<960, 256, 0, stream>>>(uwp, Pu, 384, 128, 64);
  adj_softmax<<<2048, 256, 0, stream>>>(emb, adjH, adjL);
  split_xt<<<dim3(32, 32), 256, 0, stream>>>(x, Sh, Sl);

  // Xg1 = A@x (2-prod) ; Xg2r = A@Xg1 raw (3-prod); consumers apply 2v-x
  fgemm<0, 1><<<dim3(32, 16), 256, 0, stream>>>(adjH, nullptr, Sh, Sl, Xg1f, 2048, 2048);
  tsplit<<<dim3(32, 32), 256, 0, stream>>>(Xg1f, Sh, Sl, 2048, 2048);
  fgemm<1, 1><<<dim3(32, 16), 256, 0, stream>>>(adjH, adjL, Sh, Sl, Xg2r, 2048, 2048);

  gate_kernel<<<4096, 256, 0, stream>>>(x, Xg1f, Xg2r, Pg, gbp, emb, Zf, rb);

  // Cgz1 = A@z (2-prod) ; Cgz2r = A@Cgz1 raw (3-prod); update applies 2v-z
  tsplit<<<dim3(32, 32), 256, 0, stream>>>(Zf, Sh, Sl, 2048, 2048);
  fgemm<0, 1><<<dim3(32, 16), 256, 0, stream>>>(adjH, nullptr, Sh, Sl, Cgz1f, 2048, 2048);
  tsplit<<<dim3(32, 32), 256, 0, stream>>>(Cgz1f, Sh, Sl, 2048, 2048);
  fgemm<1, 1><<<dim3(32, 16), 256, 0, stream>>>(adjH, adjL, Sh, Sl, Cgz2r, 2048, 2048);

  // adj + S now dead -> materialize update W into their region
  wgen<<<dim3(24, 128), 256, 0, stream>>>(Pu, emb, Wu);
  update_kernel<<<4096, 256, 0, stream>>>(x, Zf, Xg1f, Cgz1f, Xg2r, Cgz2r, Wu,
                                          ubp, emb, rb, out);
}

// Round 8
// 520.434 us; speedup vs baseline: 1.4666x; 1.1314x over previous
//
#include <hip/hip_runtime.h>
#include <hip/hip_bf16.h>

typedef __hip_bfloat16 bf16_t;
typedef float f32x4 __attribute__((ext_vector_type(4)));
typedef __bf16 bf16x8 __attribute__((ext_vector_type(8)));

#define AS1 __attribute__((address_space(1)))
#define AS3 __attribute__((address_space(3)))

__device__ __forceinline__ void gload_lds16(const void* g, void* l) {
  __builtin_amdgcn_global_load_lds((const AS1 void*)g, (AS3 void*)l, 16, 0, 0);
}

__device__ __forceinline__ bf16_t f2b(float v) { return __float2bfloat16(v); }
__device__ __forceinline__ float b2f(bf16_t v) { return __bfloat162float(v); }

// ------------- adj = softmax(relu(E E^T), axis=1), hi/lo bf16 planes -------
__global__ __launch_bounds__(256) void adj_softmax(const float* __restrict__ emb,
                                                   bf16_t* __restrict__ adjH,
                                                   bf16_t* __restrict__ adjL) {
  __shared__ float vals[2048];
  __shared__ float red[16];
  const int n = blockIdx.x;
  const int t = threadIdx.x;
  const int lane = t & 63, wave = t >> 6;
  float en[10];
#pragma unroll
  for (int e = 0; e < 10; ++e) en[e] = emb[n * 10 + e];
  float lm = 0.0f;
  for (int m = t; m < 2048; m += 256) {
    const float* em = emb + m * 10;
    float d = 0.f;
#pragma unroll
    for (int e = 0; e < 10; ++e) d += en[e] * em[e];
    d = fmaxf(d, 0.0f);
    vals[m] = d;
    lm = fmaxf(lm, d);
  }
#pragma unroll
  for (int off = 32; off > 0; off >>= 1) lm = fmaxf(lm, __shfl_down(lm, off));
  if (lane == 0) red[wave] = lm;
  __syncthreads();
  const float gmax = fmaxf(fmaxf(red[0], red[1]), fmaxf(red[2], red[3]));
  float ls = 0.f;
  for (int m = t; m < 2048; m += 256) {
    float ev = expf(vals[m] - gmax);
    vals[m] = ev;
    ls += ev;
  }
#pragma unroll
  for (int off = 32; off > 0; off >>= 1) ls += __shfl_down(ls, off);
  if (lane == 0) red[8 + wave] = ls;
  __syncthreads();
  const float inv = 1.0f / (red[8] + red[9] + red[10] + red[11]);
  for (int m = t; m < 2048; m += 256) {
    float v = vals[m] * inv;
    bf16_t h = f2b(v);
    adjH[(long)n * 2048 + m] = h;
    adjL[(long)n * 2048 + m] = f2b(v - b2f(h));
  }
}

// ------------- XT[b*64+i][m] = x[b][m][i], hi/lo planes --------------------
__global__ __launch_bounds__(256) void split_xt(const float* __restrict__ x,
                                                bf16_t* __restrict__ XTh,
                                                bf16_t* __restrict__ XTl) {
  __shared__ float tile[64][65];
  const int m0 = blockIdx.x * 64;
  const int b = blockIdx.y;
  const int tx = threadIdx.x & 63, ty = threadIdx.x >> 6;
  for (int r = ty; r < 64; r += 4)
    tile[r][tx] = x[(long)b * 131072 + (long)(m0 + r) * 64 + tx];
  __syncthreads();
  for (int r = ty; r < 64; r += 4) {
    float v = tile[tx][r];
    bf16_t h = f2b(v);
    long idx = (long)(b * 64 + r) * 2048 + m0 + tx;
    XTh[idx] = h;
    XTl[idx] = f2b(v - b2f(h));
  }
}

// ------------- generic fp32 transpose-split: out[c][r] = in[r][c] ----------
__global__ __launch_bounds__(256) void tsplit(const float* __restrict__ in,
                                              bf16_t* __restrict__ oH,
                                              bf16_t* __restrict__ oL, int R, int C) {
  __shared__ float tile[64][65];
  const int c0 = blockIdx.x * 64, r0 = blockIdx.y * 64;
  const int tx = threadIdx.x & 63, ty = threadIdx.x >> 6;
  for (int r = ty; r < 64; r += 4)
    tile[r][tx] = in[(long)(r0 + r) * C + c0 + tx];
  __syncthreads();
  for (int r = ty; r < 64; r += 4) {
    float v = tile[tx][r];
    bf16_t h = f2b(v);
    long idx = (long)(c0 + r) * R + r0 + tx;
    oH[idx] = h;
    oL[idx] = f2b(v - b2f(h));
  }
}

// ------------- permute w_pool (E,3,I,O) -> P[e][o*KI + k*I+i], fp32 --------
__global__ __launch_bounds__(256) void permute_pool(const float* __restrict__ wp,
                                                    float* __restrict__ P,
                                                    int KI, int I, int O) {
  const int g = blockIdx.x * 256 + threadIdx.x;
  const int per = KI * O;  // 24576
  const int e = g / per, rem = g % per;
  const int o = rem / KI, kk = rem % KI;
  const int k = kk / I, i = kk % I;
  P[g] = wp[(long)((e * 3 + k) * I + i) * O + o];
}

// ------------- W[n][c] = bf16(sum_e emb[n,e] * P[e][c]) --------------------
// Output: 2048 x 24576 bf16 = 100,663,296 BYTES (96 MiB).
__global__ __launch_bounds__(256) void wgen(const float* __restrict__ P,
                                            const float* __restrict__ emb,
                                            bf16_t* __restrict__ W) {
  __shared__ float Ps[10 * 1024];
  __shared__ float es[160];
  const int c0 = blockIdx.x * 1024;
  const int n0 = blockIdx.y * 16;
  const int t = threadIdx.x;
  for (int g = t; g < 10240; g += 256) {
    int e = g >> 10, idx = g & 1023;
    Ps[g] = P[(long)e * 24576 + c0 + idx];
  }
  if (t < 160) es[t] = emb[n0 * 10 + t];
  __syncthreads();
  for (int nn = 0; nn < 16; ++nn) {
    float e0 = es[nn * 10 + 0], e1 = es[nn * 10 + 1], e2 = es[nn * 10 + 2],
          e3 = es[nn * 10 + 3], e4 = es[nn * 10 + 4], e5 = es[nn * 10 + 5],
          e6 = es[nn * 10 + 6], e7 = es[nn * 10 + 7], e8 = es[nn * 10 + 8],
          e9 = es[nn * 10 + 9];
#pragma unroll
    for (int q = 0; q < 4; ++q) {
      int idx = q * 256 + t;
      float v = e0 * Ps[idx] + e1 * Ps[1024 + idx] + e2 * Ps[2048 + idx] +
                e3 * Ps[3072 + idx] + e4 * Ps[4096 + idx] + e5 * Ps[5120 + idx] +
                e6 * Ps[6144 + idx] + e7 * Ps[7168 + idx] + e8 * Ps[8192 + idx] +
                e9 * Ps[9216 + idx];
      W[(long)(n0 + nn) * 24576 + c0 + idx] = f2b(v);
    }
  }
}

// ------------- fused multi-product GEMM (128x64 tile, raw fp32 out) --------
// C[i,j] = sum_k A[i,k]*B[j,k]; products Ah*Bh (+Ah*Bl if BLO) (+Al*Bh if ALO)
// grid (N/64, M/128), 256 threads.
template <int ALO, int BLO>
__global__ __launch_bounds__(256) void fgemm(const bf16_t* __restrict__ Ah,
                                             const bf16_t* __restrict__ Al,
                                             const bf16_t* __restrict__ Bh,
                                             const bf16_t* __restrict__ Bl,
                                             float* __restrict__ Cf, int K, int ldc) {
  __shared__ __align__(16) bf16_t Ash[128 * 32];
  __shared__ __align__(16) bf16_t Asl[128 * 32];
  __shared__ __align__(16) bf16_t Bsh[64 * 32];
  __shared__ __align__(16) bf16_t Bsl[64 * 32];
  const int t = threadIdx.x;
  const int wave = t >> 6, lane = t & 63;
  const long m0 = (long)blockIdx.y * 128;
  const long n0 = (long)blockIdx.x * 64;
  const int srow = t >> 2;
  const int skb = (t & 3) * 8;
  const long aoff = (m0 + srow) * K + skb;
  const long boff = (n0 + srow) * K + skb;
  const int wm = wave * 32;
  const int fr = lane & 15, qk = (lane >> 4) * 8;
  char* lAh = (char*)Ash + wave * 1024;
  char* lAl = (char*)Asl + wave * 1024;
  char* lBh = (char*)Bsh + wave * 1024;
  char* lBl = (char*)Bsl + wave * 1024;
  f32x4 acc[2][4] = {};
  for (int k0 = 0; k0 < K; k0 += 32) {
    gload_lds16(Ah + aoff + k0, lAh);
    gload_lds16(Ah + aoff + (long)64 * K + k0, lAh + 4096);
    gload_lds16(Bh + boff + k0, lBh);
    if (ALO) {
      gload_lds16(Al + aoff + k0, lAl);
      gload_lds16(Al + aoff + (long)64 * K + k0, lAl + 4096);
    }
    if (BLO) gload_lds16(Bl + boff + k0, lBl);
    __syncthreads();
    bf16x8 ah[2], bh[4];
#pragma unroll
    for (int i = 0; i < 2; ++i)
      ah[i] = *(const bf16x8*)(Ash + (wm + i * 16 + fr) * 32 + qk);
#pragma unroll
    for (int j = 0; j < 4; ++j)
      bh[j] = *(const bf16x8*)(Bsh + (j * 16 + fr) * 32 + qk);
#pragma unroll
    for (int i = 0; i < 2; ++i)
#pragma unroll
      for (int j = 0; j < 4; ++j)
        acc[i][j] = __builtin_amdgcn_mfma_f32_16x16x32_bf16(ah[i], bh[j], acc[i][j], 0, 0, 0);
    if (BLO) {
      bf16x8 bl[4];
#pragma unroll
      for (int j = 0; j < 4; ++j)
        bl[j] = *(const bf16x8*)(Bsl + (j * 16 + fr) * 32 + qk);
#pragma unroll
      for (int i = 0; i < 2; ++i)
#pragma unroll
        for (int j = 0; j < 4; ++j)
          acc[i][j] = __builtin_amdgcn_mfma_f32_16x16x32_bf16(ah[i], bl[j], acc[i][j], 0, 0, 0);
    }
    if (ALO) {
      bf16x8 al[2];
#pragma unroll
      for (int i = 0; i < 2; ++i)
        al[i] = *(const bf16x8*)(Asl + (wm + i * 16 + fr) * 32 + qk);
#pragma unroll
      for (int i = 0; i < 2; ++i)
#pragma unroll
        for (int j = 0; j < 4; ++j)
          acc[i][j] = __builtin_amdgcn_mfma_f32_16x16x32_bf16(al[i], bh[j], acc[i][j], 0, 0, 0);
    }
    __syncthreads();
  }
  const int crow = (lane >> 4) * 4, ccol = lane & 15;
#pragma unroll
  for (int i = 0; i < 2; ++i)
#pragma unroll
    for (int j = 0; j < 4; ++j)
#pragma unroll
      for (int r = 0; r < 4; ++r) {
        long gm = m0 + wm + i * 16 + crow + r;
        long gn = n0 + j * 16 + ccol;
        Cf[gm * ldc + gn] = acc[i][j][r];
      }
}

// ------------- gate (o-split): (32x192)@W_half(192x64)+bias, sigmoid -------
// grid 4096: block = (n, oh).  A = [x | Xg1 | 2*Xg2raw - x] fp32 -> hi/lo in
// LDS (25.6 KB).  W streamed from materialized Wg (global, no LDS stage).
__global__ __launch_bounds__(256) void gate_kernel(
    const float* __restrict__ x, const float* __restrict__ Xg1f,
    const float* __restrict__ Xg2r, const bf16_t* __restrict__ Wg,
    const float* __restrict__ bpool, const float* __restrict__ emb,
    float* __restrict__ Zf, bf16_t* __restrict__ rb) {
  __shared__ __align__(16) bf16_t Ahi[32 * 200];
  __shared__ __align__(16) bf16_t Alo[32 * 200];
  const int n = blockIdx.x >> 1;
  const int oh = blockIdx.x & 1;
  const int t = threadIdx.x;
  float en[10];
#pragma unroll
  for (int e = 0; e < 10; ++e) en[e] = emb[n * 10 + e];
  {
    const int b = t >> 3, i8 = (t & 7) * 8;
    const float* s0 = x + (long)b * 131072 + (long)n * 64 + i8;
    const float* s1 = Xg1f + (long)n * 2048 + b * 64 + i8;
    const float* s2 = Xg2r + (long)n * 2048 + b * 64 + i8;
    float v0[8], v1[8], v2[8];
#pragma unroll
    for (int j = 0; j < 8; ++j) v0[j] = s0[j];
#pragma unroll
    for (int j = 0; j < 8; ++j) v1[j] = s1[j];
#pragma unroll
    for (int j = 0; j < 8; ++j) v2[j] = 2.0f * s2[j] - v0[j];
    union { uint4 u; bf16_t h[8]; } th, tl;
#pragma unroll
    for (int j = 0; j < 8; ++j) {
      bf16_t h = f2b(v0[j]); th.h[j] = h; tl.h[j] = f2b(v0[j] - b2f(h));
    }
    *(uint4*)(Ahi + b * 200 + i8) = th.u;
    *(uint4*)(Alo + b * 200 + i8) = tl.u;
#pragma unroll
    for (int j = 0; j < 8; ++j) {
      bf16_t h = f2b(v1[j]); th.h[j] = h; tl.h[j] = f2b(v1[j] - b2f(h));
    }
    *(uint4*)(Ahi + b * 200 + 64 + i8) = th.u;
    *(uint4*)(Alo + b * 200 + 64 + i8) = tl.u;
#pragma unroll
    for (int j = 0; j < 8; ++j) {
      bf16_t h = f2b(v2[j]); th.h[j] = h; tl.h[j] = f2b(v2[j] - b2f(h));
    }
    *(uint4*)(Ahi + b * 200 + 128 + i8) = th.u;
    *(uint4*)(Alo + b * 200 + 128 + i8) = tl.u;
  }
  __syncthreads();
  const int wave = t >> 6, lane = t & 63;
  const int ob = wave * 16;
  const int fr = lane & 15, qk = (lane >> 4) * 8;
  const bf16_t* Wp = Wg + (long)n * 24576 + (long)oh * 12288 + (ob + fr) * 192 + qk;
  f32x4 acc[2] = {};
#pragma unroll
  for (int k0 = 0; k0 < 192; k0 += 32) {
    bf16x8 bh = *(const bf16x8*)(Wp + k0);
    bf16x8 a0h = *(const bf16x8*)(Ahi + fr * 200 + k0 + qk);
    bf16x8 a1h = *(const bf16x8*)(Ahi + (16 + fr) * 200 + k0 + qk);
    bf16x8 a0l = *(const bf16x8*)(Alo + fr * 200 + k0 + qk);
    bf16x8 a1l = *(const bf16x8*)(Alo + (16 + fr) * 200 + k0 + qk);
    acc[0] = __builtin_amdgcn_mfma_f32_16x16x32_bf16(a0h, bh, acc[0], 0, 0, 0);
    acc[0] = __builtin_amdgcn_mfma_f32_16x16x32_bf16(a0l, bh, acc[0], 0, 0, 0);
    acc[1] = __builtin_amdgcn_mfma_f32_16x16x32_bf16(a1h, bh, acc[1], 0, 0, 0);
    acc[1] = __builtin_amdgcn_mfma_f32_16x16x32_bf16(a1l, bh, acc[1], 0, 0, 0);
  }
  const int quad = lane >> 4;
  const int o_loc = ob + fr;
  const int o_glob = oh * 64 + o_loc;
  float bias = 0.f;
#pragma unroll
  for (int e = 0; e < 10; ++e) bias += en[e] * bpool[e * 128 + o_glob];
#pragma unroll
  for (int i2 = 0; i2 < 2; ++i2)
#pragma unroll
    for (int r = 0; r < 4; ++r) {
      const int b = i2 * 16 + quad * 4 + r;
      float v = acc[i2][r] + bias;
      v = 1.0f / (1.0f + expf(-v));
      if (oh == 0)
        Zf[(long)n * 2048 + b * 64 + o_loc] = v;
      else
        rb[(long)n * 2048 + b * 64 + o_loc] = f2b(v);
    }
}

// ------------- update: (32x384)@W_half(384x32), tanh, GRU blend ------------
// grid 4096: block = (n, oh).  A = [x|z | Xg1|Cgz1 | 2*Xg2r-x | 2*Cgz2r-z]
// fp32 -> hi/lo in LDS (49 KB).  W streamed from global Wu.
__global__ __launch_bounds__(256) void update_kernel(
    const float* __restrict__ x, const float* __restrict__ Zf,
    const float* __restrict__ Xg1f, const float* __restrict__ Cgz1f,
    const float* __restrict__ Xg2r, const float* __restrict__ Cgz2r,
    const bf16_t* __restrict__ Wu, const float* __restrict__ bpool,
    const float* __restrict__ emb, const bf16_t* __restrict__ rb,
    float* __restrict__ out) {
  __shared__ __align__(16) bf16_t Ahi[32 * 392];
  __shared__ __align__(16) bf16_t Alo[32 * 392];
  const int n = blockIdx.x >> 1;
  const int oh = blockIdx.x & 1;
  const int t = threadIdx.x;
  float en[10];
#pragma unroll
  for (int e = 0; e < 10; ++e) en[e] = emb[n * 10 + e];
#pragma unroll
  for (int r = 0; r < 2; ++r) {
    const int c = r * 2048 + t * 8;  // (b, j) over 32 x 128
    const int b = c >> 7, j = c & 127;
    const int lo64 = j & 63;
    const float* s0 = (j < 64) ? (x + (long)b * 131072 + (long)n * 64 + lo64)
                               : (Zf + (long)n * 2048 + b * 64 + lo64);
    const float* s1 = (j < 64) ? (Xg1f + (long)n * 2048 + b * 64 + lo64)
                               : (Cgz1f + (long)n * 2048 + b * 64 + lo64);
    const float* s2 = (j < 64) ? (Xg2r + (long)n * 2048 + b * 64 + lo64)
                               : (Cgz2r + (long)n * 2048 + b * 64 + lo64);
    float v0[8], v1[8], v2[8];
#pragma unroll
    for (int q = 0; q < 8; ++q) v0[q] = s0[q];
#pragma unroll
    for (int q = 0; q < 8; ++q) v1[q] = s1[q];
#pragma unroll
    for (int q = 0; q < 8; ++q) v2[q] = 2.0f * s2[q] - v0[q];
    union { uint4 u; bf16_t h[8]; } th, tl;
#pragma unroll
    for (int q = 0; q < 8; ++q) {
      bf16_t h = f2b(v0[q]); th.h[q] = h; tl.h[q] = f2b(v0[q] - b2f(h));
    }
    *(uint4*)(Ahi + b * 392 + j) = th.u;
    *(uint4*)(Alo + b * 392 + j) = tl.u;
#pragma unroll
    for (int q = 0; q < 8; ++q) {
      bf16_t h = f2b(v1[q]); th.h[q] = h; tl.h[q] = f2b(v1[q] - b2f(h));
    }
    *(uint4*)(Ahi + b * 392 + 128 + j) = th.u;
    *(uint4*)(Alo + b * 392 + 128 + j) = tl.u;
#pragma unroll
    for (int q = 0; q < 8; ++q) {
      bf16_t h = f2b(v2[q]); th.h[q] = h; tl.h[q] = f2b(v2[q] - b2f(h));
    }
    *(uint4*)(Ahi + b * 392 + 256 + j) = th.u;
    *(uint4*)(Alo + b * 392 + 256 + j) = tl.u;
  }
  __syncthreads();
  const int wave = t >> 6, lane = t & 63;
  const int mh = (wave >> 1) * 16;
  const int ob = (wave & 1) * 16;
  const int fr = lane & 15, qk = (lane >> 4) * 8;
  const bf16_t* Wp = Wu + (long)n * 24576 + (long)oh * 12288 + (ob + fr) * 384 + qk;
  f32x4 acc = {};
#pragma unroll
  for (int k0 = 0; k0 < 384; k0 += 32) {
    bf16x8 bh = *(const bf16x8*)(Wp + k0);
    bf16x8 ah = *(const bf16x8*)(Ahi + (mh + fr) * 392 + k0 + qk);
    bf16x8 al = *(const bf16x8*)(Alo + (mh + fr) * 392 + k0 + qk);
    acc = __builtin_amdgcn_mfma_f32_16x16x32_bf16(ah, bh, acc, 0, 0, 0);
    acc = __builtin_amdgcn_mfma_f32_16x16x32_bf16(al, bh, acc, 0, 0, 0);
  }
  const int quad = lane >> 4;
  const int og = oh * 32 + ob + fr;
  float bias = 0.f;
#pragma unroll
  for (int e = 0; e < 10; ++e) bias += en[e] * bpool[e * 64 + og];
#pragma unroll
  for (int r = 0; r < 4; ++r) {
    const int b = mh + quad * 4 + r;
    float hc = tanhf(acc[r] + bias);
    float rr = b2f(rb[(long)n * 2048 + b * 64 + og]);
    float xv = x[(long)b * 131072 + (long)n * 64 + og];
    out[(long)b * 131072 + (long)n * 64 + og] = rr * xv + (1.0f - rr) * hc;
  }
}

extern "C" void kernel_launch(void* const* d_in, const int* in_sizes, int n_in,
                              void* d_out, int out_size, void* d_ws, size_t ws_size,
                              hipStream_t stream) {
  (void)in_sizes; (void)n_in; (void)out_size;
  const float* x   = (const float*)d_in[0];
  const float* emb = (const float*)d_in[2];
  const float* gwp = (const float*)d_in[3];
  const float* gbp = (const float*)d_in[4];
  const float* uwp = (const float*)d_in[5];
  const float* ubp = (const float*)d_in[6];
  float* out = (float*)d_out;
  char* ws = (char*)d_ws;

  // high-water 194,904,064 B (round-6-proven ws_size >= this). Guard:
  if (ws_size < 194904064ull) return;

  // ---- live-range-checked layout (W buffers are 96 MiB EACH) ----
  float*  Xg1f  = (float*)(ws);                  // 16 MiB [0, 16.8M)   alive: fgemm1 -> update
  float*  Xg2r  = (float*)(ws + 16777216);       // 16 MiB [16.8,33.6M) alive: fgemm2 -> update
  float*  Zf    = (float*)(ws + 33554432);       // 16 MiB [33.6,50.3M) alive: gate -> update
  bf16_t* rb    = (bf16_t*)(ws + 50331648);      //  8 MiB [50.3,58.7M) alive: gate -> update
  float*  Pg    = (float*)(ws + 58720256);       // 983040 [58.7,59.7M) dead after wgen#1
  float*  Pu    = (float*)(ws + 59703296);       // 983040 [59.7,60.7M) dead after wgen#2
  // Wu 96 MiB [60.7M, 161.3M): born at wgen#2, AFTER adj/S/Wg-head are dead.
  bf16_t* Wu    = (bf16_t*)(ws + 60686336);
  //   overlays (alive adj_softmax -> last fgemm):
  bf16_t* adjH  = (bf16_t*)(ws + 60686336);      //  8 MiB
  bf16_t* adjL  = (bf16_t*)(ws + 69074944);      //  8 MiB
  char*   S     = ws + 77463552;                 // 16 MiB transpose scratch
  // Wg 96 MiB [94.2M, 194.9M): born wgen#1, dead after gate.
  bf16_t* Wg    = (bf16_t*)(ws + 94240768);
  //   tail overlays (born after gate -> alive into update):
  float*  Cgz1f = (float*)(ws + 161349632);      // 16 MiB [161.3,178.1M)
  float*  Cgz2r = (float*)(ws + 178126848);      // 16 MiB [178.1,194.9M)
  bf16_t* Sh    = (bf16_t*)S;                    // hi plane (8 MiB)
  bf16_t* Sl    = (bf16_t*)(S + 8388608);        // lo plane (8 MiB)

  permute_pool<<<960, 256, 0, stream>>>(gwp, Pg, 192, 64, 128);
  permute_pool<<<960, 256, 0, stream>>>(uwp, Pu, 384, 128, 64);
  wgen<<<dim3(24, 128), 256, 0, stream>>>(Pg, emb, Wg);  // materialize gate W (96 MiB)
  adj_softmax<<<2048, 256, 0, stream>>>(emb, adjH, adjL);
  split_xt<<<dim3(32, 32), 256, 0, stream>>>(x, Sh, Sl);

  // Xg1 = A@x (2-prod) ; Xg2r = A@Xg1 raw (3-prod); consumers apply 2v-x
  fgemm<0, 1><<<dim3(32, 16), 256, 0, stream>>>(adjH, nullptr, Sh, Sl, Xg1f, 2048, 2048);
  tsplit<<<dim3(32, 32), 256, 0, stream>>>(Xg1f, Sh, Sl, 2048, 2048);
  fgemm<1, 1><<<dim3(32, 16), 256, 0, stream>>>(adjH, adjL, Sh, Sl, Xg2r, 2048, 2048);

  gate_kernel<<<4096, 256, 0, stream>>>(x, Xg1f, Xg2r, Wg, gbp, emb, Zf, rb);
  // Wg dead from here; its tail now hosts Cgz1f/Cgz2r.

  // Cgz1 = A@z (2-prod) ; Cgz2r = A@Cgz1 raw (3-prod); update applies 2v-z
  tsplit<<<dim3(32, 32), 256, 0, stream>>>(Zf, Sh, Sl, 2048, 2048);
  fgemm<0, 1><<<dim3(32, 16), 256, 0, stream>>>(adjH, nullptr, Sh, Sl, Cgz1f, 2048, 2048);
  tsplit<<<dim3(32, 32), 256, 0, stream>>>(Cgz1f, Sh, Sl, 2048, 2048);
  fgemm<1, 1><<<dim3(32, 16), 256, 0, stream>>>(adjH, adjL, Sh, Sl, Cgz2r, 2048, 2048);
  // adj + S + Wg-head dead from here; Wu may be materialized over them.

  wgen<<<dim3(24, 128), 256, 0, stream>>>(Pu, emb, Wu);  // materialize update W (96 MiB)
  update_kernel<<<4096, 256, 0, stream>>>(x, Zf, Xg1f, Cgz1f, Xg2r, Cgz2r, Wu,
                                          ubp, emb, rb, out);
}

// Round 9
// 517.622 us; speedup vs baseline: 1.4746x; 1.0054x over previous
//
#include <hip/hip_runtime.h>
#include <hip/hip_bf16.h>

typedef __hip_bfloat16 bf16_t;
typedef float f32x4 __attribute__((ext_vector_type(4)));
typedef __bf16 bf16x8 __attribute__((ext_vector_type(8)));

#define AS1 __attribute__((address_space(1)))
#define AS3 __attribute__((address_space(3)))

__device__ __forceinline__ void gload_lds16(const void* g, void* l) {
  __builtin_amdgcn_global_load_lds((const AS1 void*)g, (AS3 void*)l, 16, 0, 0);
}

__device__ __forceinline__ bf16_t f2b(float v) { return __float2bfloat16(v); }
__device__ __forceinline__ float b2f(bf16_t v) { return __bfloat162float(v); }

// ------------- adj = softmax(relu(E E^T), axis=1), hi/lo bf16 planes -------
__global__ __launch_bounds__(256) void adj_softmax(const float* __restrict__ emb,
                                                   bf16_t* __restrict__ adjH,
                                                   bf16_t* __restrict__ adjL) {
  __shared__ float vals[2048];
  __shared__ float red[16];
  const int n = blockIdx.x;
  const int t = threadIdx.x;
  const int lane = t & 63, wave = t >> 6;
  float en[10];
#pragma unroll
  for (int e = 0; e < 10; ++e) en[e] = emb[n * 10 + e];
  float lm = 0.0f;
  for (int m = t; m < 2048; m += 256) {
    const float* em = emb + m * 10;
    float d = 0.f;
#pragma unroll
    for (int e = 0; e < 10; ++e) d += en[e] * em[e];
    d = fmaxf(d, 0.0f);
    vals[m] = d;
    lm = fmaxf(lm, d);
  }
#pragma unroll
  for (int off = 32; off > 0; off >>= 1) lm = fmaxf(lm, __shfl_down(lm, off));
  if (lane == 0) red[wave] = lm;
  __syncthreads();
  const float gmax = fmaxf(fmaxf(red[0], red[1]), fmaxf(red[2], red[3]));
  float ls = 0.f;
  for (int m = t; m < 2048; m += 256) {
    float ev = expf(vals[m] - gmax);
    vals[m] = ev;
    ls += ev;
  }
#pragma unroll
  for (int off = 32; off > 0; off >>= 1) ls += __shfl_down(ls, off);
  if (lane == 0) red[8 + wave] = ls;
  __syncthreads();
  const float inv = 1.0f / (red[8] + red[9] + red[10] + red[11]);
  for (int m = t; m < 2048; m += 256) {
    float v = vals[m] * inv;
    bf16_t h = f2b(v);
    adjH[(long)n * 2048 + m] = h;
    adjL[(long)n * 2048 + m] = f2b(v - b2f(h));
  }
}

// ------------- XT[b*64+i][m] = x[b][m][i], hi/lo planes --------------------
__global__ __launch_bounds__(256) void split_xt(const float* __restrict__ x,
                                                bf16_t* __restrict__ XTh,
                                                bf16_t* __restrict__ XTl) {
  __shared__ float tile[64][65];
  const int m0 = blockIdx.x * 64;
  const int b = blockIdx.y;
  const int tx = threadIdx.x & 63, ty = threadIdx.x >> 6;
  for (int r = ty; r < 64; r += 4)
    tile[r][tx] = x[(long)b * 131072 + (long)(m0 + r) * 64 + tx];
  __syncthreads();
  for (int r = ty; r < 64; r += 4) {
    float v = tile[tx][r];
    bf16_t h = f2b(v);
    long idx = (long)(b * 64 + r) * 2048 + m0 + tx;
    XTh[idx] = h;
    XTl[idx] = f2b(v - b2f(h));
  }
}

// ------------- generic fp32 transpose-split: out[c][r] = in[r][c] ----------
__global__ __launch_bounds__(256) void tsplit(const float* __restrict__ in,
                                              bf16_t* __restrict__ oH,
                                              bf16_t* __restrict__ oL, int R, int C) {
  __shared__ float tile[64][65];
  const int c0 = blockIdx.x * 64, r0 = blockIdx.y * 64;
  const int tx = threadIdx.x & 63, ty = threadIdx.x >> 6;
  for (int r = ty; r < 64; r += 4)
    tile[r][tx] = in[(long)(r0 + r) * C + c0 + tx];
  __syncthreads();
  for (int r = ty; r < 64; r += 4) {
    float v = tile[tx][r];
    bf16_t h = f2b(v);
    long idx = (long)(c0 + r) * R + r0 + tx;
    oH[idx] = h;
    oL[idx] = f2b(v - b2f(h));
  }
}

// ------------- permute w_pool (E,3,I,O) -> P[e][o*KI + k*I+i], fp32 --------
__global__ __launch_bounds__(256) void permute_pool(const float* __restrict__ wp,
                                                    float* __restrict__ P,
                                                    int KI, int I, int O) {
  const int g = blockIdx.x * 256 + threadIdx.x;
  const int per = KI * O;  // 24576
  const int e = g / per, rem = g % per;
  const int o = rem / KI, kk = rem % KI;
  const int k = kk / I, i = kk % I;
  P[g] = wp[(long)((e * 3 + k) * I + i) * O + o];
}

// ------------- W[n][c] = bf16(sum_e emb[n,e] * P[e][c]) --------------------
// Output: 2048 x 24576 bf16 = 100,663,296 BYTES (96 MiB).
__global__ __launch_bounds__(256) void wgen(const float* __restrict__ P,
                                            const float* __restrict__ emb,
                                            bf16_t* __restrict__ W) {
  __shared__ float Ps[10 * 1024];
  __shared__ float es[160];
  const int c0 = blockIdx.x * 1024;
  const int n0 = blockIdx.y * 16;
  const int t = threadIdx.x;
  for (int g = t; g < 10240; g += 256) {
    int e = g >> 10, idx = g & 1023;
    Ps[g] = P[(long)e * 24576 + c0 + idx];
  }
  if (t < 160) es[t] = emb[n0 * 10 + t];
  __syncthreads();
  for (int nn = 0; nn < 16; ++nn) {
    float e0 = es[nn * 10 + 0], e1 = es[nn * 10 + 1], e2 = es[nn * 10 + 2],
          e3 = es[nn * 10 + 3], e4 = es[nn * 10 + 4], e5 = es[nn * 10 + 5],
          e6 = es[nn * 10 + 6], e7 = es[nn * 10 + 7], e8 = es[nn * 10 + 8],
          e9 = es[nn * 10 + 9];
#pragma unroll
    for (int q = 0; q < 4; ++q) {
      int idx = q * 256 + t;
      float v = e0 * Ps[idx] + e1 * Ps[1024 + idx] + e2 * Ps[2048 + idx] +
                e3 * Ps[3072 + idx] + e4 * Ps[4096 + idx] + e5 * Ps[5120 + idx] +
                e6 * Ps[6144 + idx] + e7 * Ps[7168 + idx] + e8 * Ps[8192 + idx] +
                e9 * Ps[9216 + idx];
      W[(long)(n0 + nn) * 24576 + c0 + idx] = f2b(v);
    }
  }
}

// ------------- fused multi-product GEMM v2 ---------------------------------
// 64x64 tile, BK=64, XOR-swizzled LDS.  C[i,j] = sum_k A[i,k]*B[j,k];
// products Ah*Bh (+Ah*Bl if BLO) (+Al*Bh if ALO).  grid (N/64, M/64).
// LDS plane = two 4KB halves [kh][row 64][32]; logical chunk c (8 bf16) of
// row r lives at slot c ^ ((r>>1)&3)  ->  2-way max bank alias on reads.
template <int ALO, int BLO>
__global__ __launch_bounds__(256) void fgemm(const bf16_t* __restrict__ Ah,
                                             const bf16_t* __restrict__ Al,
                                             const bf16_t* __restrict__ Bh,
                                             const bf16_t* __restrict__ Bl,
                                             float* __restrict__ Cf, int K, int ldc) {
  __shared__ __align__(16) bf16_t Ash[64 * 64];
  __shared__ __align__(16) bf16_t Asl[ALO ? 64 * 64 : 8];
  __shared__ __align__(16) bf16_t Bsh[64 * 64];
  __shared__ __align__(16) bf16_t Bsl[BLO ? 64 * 64 : 8];
  const int t = threadIdx.x;
  const int wave = t >> 6, lane = t & 63;
  const long m0 = (long)blockIdx.y * 64;
  const long n0 = (long)blockIdx.x * 64;
  const int srow = t >> 2;                             // local row 0..63
  const int sc = ((t & 3) ^ ((t >> 3) & 3)) << 3;      // swizzled src chunk (elems)
  const long aoff = (m0 + srow) * K + sc;
  const long boff = (n0 + srow) * K + sc;
  const int wm = (wave >> 1) * 32;
  const int wn = (wave & 1) * 32;
  const int fr = lane & 15;
  const int quad = lane >> 4;
  const int swz = (quad ^ ((fr >> 1) & 3)) << 3;       // read-side swizzle (elems)
  char* lAh = (char*)Ash + wave * 1024;
  char* lAl = (char*)Asl + wave * 1024;
  char* lBh = (char*)Bsh + wave * 1024;
  char* lBl = (char*)Bsl + wave * 1024;
  f32x4 acc[2][2] = {};
  for (int k0 = 0; k0 < K; k0 += 64) {
#pragma unroll
    for (int kh = 0; kh < 2; ++kh) {
      gload_lds16(Ah + aoff + k0 + kh * 32, lAh + kh * 4096);
      gload_lds16(Bh + boff + k0 + kh * 32, lBh + kh * 4096);
      if (ALO) gload_lds16(Al + aoff + k0 + kh * 32, lAl + kh * 4096);
      if (BLO) gload_lds16(Bl + boff + k0 + kh * 32, lBl + kh * 4096);
    }
    __syncthreads();
#pragma unroll
    for (int kh = 0; kh < 2; ++kh) {
      const int kb = kh * 2048;
      bf16x8 ah[2], bh[2];
#pragma unroll
      for (int i = 0; i < 2; ++i) {
        ah[i] = *(const bf16x8*)(Ash + kb + (wm + i * 16 + fr) * 32 + swz);
        bh[i] = *(const bf16x8*)(Bsh + kb + (wn + i * 16 + fr) * 32 + swz);
      }
#pragma unroll
      for (int i = 0; i < 2; ++i)
#pragma unroll
        for (int j = 0; j < 2; ++j)
          acc[i][j] = __builtin_amdgcn_mfma_f32_16x16x32_bf16(ah[i], bh[j], acc[i][j], 0, 0, 0);
      if (BLO) {
        bf16x8 bl[2];
#pragma unroll
        for (int j = 0; j < 2; ++j)
          bl[j] = *(const bf16x8*)(Bsl + kb + (wn + j * 16 + fr) * 32 + swz);
#pragma unroll
        for (int i = 0; i < 2; ++i)
#pragma unroll
          for (int j = 0; j < 2; ++j)
            acc[i][j] = __builtin_amdgcn_mfma_f32_16x16x32_bf16(ah[i], bl[j], acc[i][j], 0, 0, 0);
      }
      if (ALO) {
        bf16x8 al[2];
#pragma unroll
        for (int i = 0; i < 2; ++i)
          al[i] = *(const bf16x8*)(Asl + kb + (wm + i * 16 + fr) * 32 + swz);
#pragma unroll
        for (int i = 0; i < 2; ++i)
#pragma unroll
          for (int j = 0; j < 2; ++j)
            acc[i][j] = __builtin_amdgcn_mfma_f32_16x16x32_bf16(al[i], bh[j], acc[i][j], 0, 0, 0);
      }
    }
    __syncthreads();
  }
  const int crow = quad * 4, ccol = fr;
#pragma unroll
  for (int i = 0; i < 2; ++i)
#pragma unroll
    for (int j = 0; j < 2; ++j)
#pragma unroll
      for (int r = 0; r < 4; ++r) {
        long gm = m0 + wm + i * 16 + crow + r;
        long gn = n0 + wn + j * 16 + ccol;
        Cf[gm * ldc + gn] = acc[i][j][r];
      }
}

// ------------- gate (o-split): (32x192)@W_half(192x64)+bias, sigmoid -------
// grid 4096: block = (n, oh).  A = [x | Xg1 | 2*Xg2raw - x] fp32 -> hi/lo in
// LDS (25.6 KB).  W streamed from materialized Wg (global, no LDS stage).
__global__ __launch_bounds__(256) void gate_kernel(
    const float* __restrict__ x, const float* __restrict__ Xg1f,
    const float* __restrict__ Xg2r, const bf16_t* __restrict__ Wg,
    const float* __restrict__ bpool, const float* __restrict__ emb,
    float* __restrict__ Zf, bf16_t* __restrict__ rb) {
  __shared__ __align__(16) bf16_t Ahi[32 * 200];
  __shared__ __align__(16) bf16_t Alo[32 * 200];
  const int n = blockIdx.x >> 1;
  const int oh = blockIdx.x & 1;
  const int t = threadIdx.x;
  float en[10];
#pragma unroll
  for (int e = 0; e < 10; ++e) en[e] = emb[n * 10 + e];
  {
    const int b = t >> 3, i8 = (t & 7) * 8;
    const float* s0 = x + (long)b * 131072 + (long)n * 64 + i8;
    const float* s1 = Xg1f + (long)n * 2048 + b * 64 + i8;
    const float* s2 = Xg2r + (long)n * 2048 + b * 64 + i8;
    float v0[8], v1[8], v2[8];
#pragma unroll
    for (int j = 0; j < 8; ++j) v0[j] = s0[j];
#pragma unroll
    for (int j = 0; j < 8; ++j) v1[j] = s1[j];
#pragma unroll
    for (int j = 0; j < 8; ++j) v2[j] = 2.0f * s2[j] - v0[j];
    union { uint4 u; bf16_t h[8]; } th, tl;
#pragma unroll
    for (int j = 0; j < 8; ++j) {
      bf16_t h = f2b(v0[j]); th.h[j] = h; tl.h[j] = f2b(v0[j] - b2f(h));
    }
    *(uint4*)(Ahi + b * 200 + i8) = th.u;
    *(uint4*)(Alo + b * 200 + i8) = tl.u;
#pragma unroll
    for (int j = 0; j < 8; ++j) {
      bf16_t h = f2b(v1[j]); th.h[j] = h; tl.h[j] = f2b(v1[j] - b2f(h));
    }
    *(uint4*)(Ahi + b * 200 + 64 + i8) = th.u;
    *(uint4*)(Alo + b * 200 + 64 + i8) = tl.u;
#pragma unroll
    for (int j = 0; j < 8; ++j) {
      bf16_t h = f2b(v2[j]); th.h[j] = h; tl.h[j] = f2b(v2[j] - b2f(h));
    }
    *(uint4*)(Ahi + b * 200 + 128 + i8) = th.u;
    *(uint4*)(Alo + b * 200 + 128 + i8) = tl.u;
  }
  __syncthreads();
  const int wave = t >> 6, lane = t & 63;
  const int ob = wave * 16;
  const int fr = lane & 15, qk = (lane >> 4) * 8;
  const bf16_t* Wp = Wg + (long)n * 24576 + (long)oh * 12288 + (ob + fr) * 192 + qk;
  f32x4 acc[2] = {};
#pragma unroll
  for (int k0 = 0; k0 < 192; k0 += 32) {
    bf16x8 bh = *(const bf16x8*)(Wp + k0);
    bf16x8 a0h = *(const bf16x8*)(Ahi + fr * 200 + k0 + qk);
    bf16x8 a1h = *(const bf16x8*)(Ahi + (16 + fr) * 200 + k0 + qk);
    bf16x8 a0l = *(const bf16x8*)(Alo + fr * 200 + k0 + qk);
    bf16x8 a1l = *(const bf16x8*)(Alo + (16 + fr) * 200 + k0 + qk);
    acc[0] = __builtin_amdgcn_mfma_f32_16x16x32_bf16(a0h, bh, acc[0], 0, 0, 0);
    acc[0] = __builtin_amdgcn_mfma_f32_16x16x32_bf16(a0l, bh, acc[0], 0, 0, 0);
    acc[1] = __builtin_amdgcn_mfma_f32_16x16x32_bf16(a1h, bh, acc[1], 0, 0, 0);
    acc[1] = __builtin_amdgcn_mfma_f32_16x16x32_bf16(a1l, bh, acc[1], 0, 0, 0);
  }
  const int quad = lane >> 4;
  const int o_loc = ob + fr;
  const int o_glob = oh * 64 + o_loc;
  float bias = 0.f;
#pragma unroll
  for (int e = 0; e < 10; ++e) bias += en[e] * bpool[e * 128 + o_glob];
#pragma unroll
  for (int i2 = 0; i2 < 2; ++i2)
#pragma unroll
    for (int r = 0; r < 4; ++r) {
      const int b = i2 * 16 + quad * 4 + r;
      float v = acc[i2][r] + bias;
      v = 1.0f / (1.0f + expf(-v));
      if (oh == 0)
        Zf[(long)n * 2048 + b * 64 + o_loc] = v;
      else
        rb[(long)n * 2048 + b * 64 + o_loc] = f2b(v);
    }
}

// ------------- update: (32x384)@W_half(384x32), tanh, GRU blend ------------
// grid 4096: block = (n, oh).  A = [x|z | Xg1|Cgz1 | 2*Xg2r-x | 2*Cgz2r-z]
// fp32 -> hi/lo in LDS (49 KB).  W streamed from global Wu.
__global__ __launch_bounds__(256) void update_kernel(
    const float* __restrict__ x, const float* __restrict__ Zf,
    const float* __restrict__ Xg1f, const float* __restrict__ Cgz1f,
    const float* __restrict__ Xg2r, const float* __restrict__ Cgz2r,
    const bf16_t* __restrict__ Wu, const float* __restrict__ bpool,
    const float* __restrict__ emb, const bf16_t* __restrict__ rb,
    float* __restrict__ out) {
  __shared__ __align__(16) bf16_t Ahi[32 * 392];
  __shared__ __align__(16) bf16_t Alo[32 * 392];
  const int n = blockIdx.x >> 1;
  const int oh = blockIdx.x & 1;
  const int t = threadIdx.x;
  float en[10];
#pragma unroll
  for (int e = 0; e < 10; ++e) en[e] = emb[n * 10 + e];
#pragma unroll
  for (int r = 0; r < 2; ++r) {
    const int c = r * 2048 + t * 8;  // (b, j) over 32 x 128
    const int b = c >> 7, j = c & 127;
    const int lo64 = j & 63;
    const float* s0 = (j < 64) ? (x + (long)b * 131072 + (long)n * 64 + lo64)
                               : (Zf + (long)n * 2048 + b * 64 + lo64);
    const float* s1 = (j < 64) ? (Xg1f + (long)n * 2048 + b * 64 + lo64)
                               : (Cgz1f + (long)n * 2048 + b * 64 + lo64);
    const float* s2 = (j < 64) ? (Xg2r + (long)n * 2048 + b * 64 + lo64)
                               : (Cgz2r + (long)n * 2048 + b * 64 + lo64);
    float v0[8], v1[8], v2[8];
#pragma unroll
    for (int q = 0; q < 8; ++q) v0[q] = s0[q];
#pragma unroll
    for (int q = 0; q < 8; ++q) v1[q] = s1[q];
#pragma unroll
    for (int q = 0; q < 8; ++q) v2[q] = 2.0f * s2[q] - v0[q];
    union { uint4 u; bf16_t h[8]; } th, tl;
#pragma unroll
    for (int q = 0; q < 8; ++q) {
      bf16_t h = f2b(v0[q]); th.h[q] = h; tl.h[q] = f2b(v0[q] - b2f(h));
    }
    *(uint4*)(Ahi + b * 392 + j) = th.u;
    *(uint4*)(Alo + b * 392 + j) = tl.u;
#pragma unroll
    for (int q = 0; q < 8; ++q) {
      bf16_t h = f2b(v1[q]); th.h[q] = h; tl.h[q] = f2b(v1[q] - b2f(h));
    }
    *(uint4*)(Ahi + b * 392 + 128 + j) = th.u;
    *(uint4*)(Alo + b * 392 + 128 + j) = tl.u;
#pragma unroll
    for (int q = 0; q < 8; ++q) {
      bf16_t h = f2b(v2[q]); th.h[q] = h; tl.h[q] = f2b(v2[q] - b2f(h));
    }
    *(uint4*)(Ahi + b * 392 + 256 + j) = th.u;
    *(uint4*)(Alo + b * 392 + 256 + j) = tl.u;
  }
  __syncthreads();
  const int wave = t >> 6, lane = t & 63;
  const int mh = (wave >> 1) * 16;
  const int ob = (wave & 1) * 16;
  const int fr = lane & 15, qk = (lane >> 4) * 8;
  const bf16_t* Wp = Wu + (long)n * 24576 + (long)oh * 12288 + (ob + fr) * 384 + qk;
  f32x4 acc = {};
#pragma unroll
  for (int k0 = 0; k0 < 384; k0 += 32) {
    bf16x8 bh = *(const bf16x8*)(Wp + k0);
    bf16x8 ah = *(const bf16x8*)(Ahi + (mh + fr) * 392 + k0 + qk);
    bf16x8 al = *(const bf16x8*)(Alo + (mh + fr) * 392 + k0 + qk);
    acc = __builtin_amdgcn_mfma_f32_16x16x32_bf16(ah, bh, acc, 0, 0, 0);
    acc = __builtin_amdgcn_mfma_f32_16x16x32_bf16(al, bh, acc, 0, 0, 0);
  }
  const int quad = lane >> 4;
  const int og = oh * 32 + ob + fr;
  float bias = 0.f;
#pragma unroll
  for (int e = 0; e < 10; ++e) bias += en[e] * bpool[e * 64 + og];
#pragma unroll
  for (int r = 0; r < 4; ++r) {
    const int b = mh + quad * 4 + r;
    float hc = tanhf(acc[r] + bias);
    float rr = b2f(rb[(long)n * 2048 + b * 64 + og]);
    float xv = x[(long)b * 131072 + (long)n * 64 + og];
    out[(long)b * 131072 + (long)n * 64 + og] = rr * xv + (1.0f - rr) * hc;
  }
}

extern "C" void kernel_launch(void* const* d_in, const int* in_sizes, int n_in,
                              void* d_out, int out_size, void* d_ws, size_t ws_size,
                              hipStream_t stream) {
  (void)in_sizes; (void)n_in; (void)out_size;
  const float* x   = (const float*)d_in[0];
  const float* emb = (const float*)d_in[2];
  const float* gwp = (const float*)d_in[3];
  const float* gbp = (const float*)d_in[4];
  const float* uwp = (const float*)d_in[5];
  const float* ubp = (const float*)d_in[6];
  float* out = (float*)d_out;
  char* ws = (char*)d_ws;

  // high-water 194,904,064 B (round-8-proven). Guard:
  if (ws_size < 194904064ull) return;

  // ---- live-range-checked layout (W buffers are 96 MiB EACH) ----
  float*  Xg1f  = (float*)(ws);                  // 16 MiB [0, 16.8M)   alive: fgemm1 -> update
  float*  Xg2r  = (float*)(ws + 16777216);       // 16 MiB [16.8,33.6M) alive: fgemm2 -> update
  float*  Zf    = (float*)(ws + 33554432);       // 16 MiB [33.6,50.3M) alive: gate -> update
  bf16_t* rb    = (bf16_t*)(ws + 50331648);      //  8 MiB [50.3,58.7M) alive: gate -> update
  float*  Pg    = (float*)(ws + 58720256);       // 983040 [58.7,59.7M) dead after wgen#1
  float*  Pu    = (float*)(ws + 59703296);       // 983040 [59.7,60.7M) dead after wgen#2
  // Wu 96 MiB [60.7M, 161.3M): born at wgen#2, AFTER adj/S/Wg-head are dead.
  bf16_t* Wu    = (bf16_t*)(ws + 60686336);
  //   overlays (alive adj_softmax -> last fgemm):
  bf16_t* adjH  = (bf16_t*)(ws + 60686336);      //  8 MiB
  bf16_t* adjL  = (bf16_t*)(ws + 69074944);      //  8 MiB
  char*   S     = ws + 77463552;                 // 16 MiB transpose scratch
  // Wg 96 MiB [94.2M, 194.9M): born wgen#1, dead after gate.
  bf16_t* Wg    = (bf16_t*)(ws + 94240768);
  //   tail overlays (born after gate -> alive into update):
  float*  Cgz1f = (float*)(ws + 161349632);      // 16 MiB [161.3,178.1M)
  float*  Cgz2r = (float*)(ws + 178126848);      // 16 MiB [178.1,194.9M)
  bf16_t* Sh    = (bf16_t*)S;                    // hi plane (8 MiB)
  bf16_t* Sl    = (bf16_t*)(S + 8388608);        // lo plane (8 MiB)

  permute_pool<<<960, 256, 0, stream>>>(gwp, Pg, 192, 64, 128);
  permute_pool<<<960, 256, 0, stream>>>(uwp, Pu, 384, 128, 64);
  wgen<<<dim3(24, 128), 256, 0, stream>>>(Pg, emb, Wg);  // materialize gate W (96 MiB)
  adj_softmax<<<2048, 256, 0, stream>>>(emb, adjH, adjL);
  split_xt<<<dim3(32, 32), 256, 0, stream>>>(x, Sh, Sl);

  // Xg1 = A@x (2-prod) ; Xg2r = A@Xg1 raw (3-prod); consumers apply 2v-x
  fgemm<0, 1><<<dim3(32, 32), 256, 0, stream>>>(adjH, nullptr, Sh, Sl, Xg1f, 2048, 2048);
  tsplit<<<dim3(32, 32), 256, 0, stream>>>(Xg1f, Sh, Sl, 2048, 2048);
  fgemm<1, 1><<<dim3(32, 32), 256, 0, stream>>>(adjH, adjL, Sh, Sl, Xg2r, 2048, 2048);

  gate_kernel<<<4096, 256, 0, stream>>>(x, Xg1f, Xg2r, Wg, gbp, emb, Zf, rb);
  // Wg dead from here; its tail now hosts Cgz1f/Cgz2r.

  // Cgz1 = A@z (2-prod) ; Cgz2r = A@Cgz1 raw (3-prod); update applies 2v-z
  tsplit<<<dim3(32, 32), 256, 0, stream>>>(Zf, Sh, Sl, 2048, 2048);
  fgemm<0, 1><<<dim3(32, 32), 256, 0, stream>>>(adjH, nullptr, Sh, Sl, Cgz1f, 2048, 2048);
  tsplit<<<dim3(32, 32), 256, 0, stream>>>(Cgz1f, Sh, Sl, 2048, 2048);
  fgemm<1, 1><<<dim3(32, 32), 256, 0, stream>>>(adjH, adjL, Sh, Sl, Cgz2r, 2048, 2048);
  // adj + S + Wg-head dead from here; Wu may be materialized over them.

  wgen<<<dim3(24, 128), 256, 0, stream>>>(Pu, emb, Wu);  // materialize update W (96 MiB)
  update_kernel<<<4096, 256, 0, stream>>>(x, Zf, Xg1f, Cgz1f, Xg2r, Cgz2r, Wu,
                                          ubp, emb, rb, out);
}

// Round 11
// 464.908 us; speedup vs baseline: 1.6418x; 1.1134x over previous
//
#include <hip/hip_runtime.h>
#include <hip/hip_bf16.h>

typedef __hip_bfloat16 bf16_t;
typedef float f32x4 __attribute__((ext_vector_type(4)));
typedef __bf16 bf16x8 __attribute__((ext_vector_type(8)));

#define AS1 __attribute__((address_space(1)))
#define AS3 __attribute__((address_space(3)))

__device__ __forceinline__ void gload_lds16(const void* g, void* l) {
  __builtin_amdgcn_global_load_lds((const AS1 void*)g, (AS3 void*)l, 16, 0, 0);
}

__device__ __forceinline__ bf16_t f2b(float v) { return __float2bfloat16(v); }
__device__ __forceinline__ float b2f(bf16_t v) { return __bfloat162float(v); }

// ------------- adj = softmax(relu(E E^T), axis=1), hi/lo bf16 planes -------
__global__ __launch_bounds__(256) void adj_softmax(const float* __restrict__ emb,
                                                   bf16_t* __restrict__ adjH,
                                                   bf16_t* __restrict__ adjL) {
  __shared__ float vals[2048];
  __shared__ float red[16];
  const int n = blockIdx.x;
  const int t = threadIdx.x;
  const int lane = t & 63, wave = t >> 6;
  float en[10];
#pragma unroll
  for (int e = 0; e < 10; ++e) en[e] = emb[n * 10 + e];
  float lm = 0.0f;
  for (int m = t; m < 2048; m += 256) {
    const float* em = emb + m * 10;
    float d = 0.f;
#pragma unroll
    for (int e = 0; e < 10; ++e) d += en[e] * em[e];
    d = fmaxf(d, 0.0f);
    vals[m] = d;
    lm = fmaxf(lm, d);
  }
#pragma unroll
  for (int off = 32; off > 0; off >>= 1) lm = fmaxf(lm, __shfl_down(lm, off));
  if (lane == 0) red[wave] = lm;
  __syncthreads();
  const float gmax = fmaxf(fmaxf(red[0], red[1]), fmaxf(red[2], red[3]));
  float ls = 0.f;
  for (int m = t; m < 2048; m += 256) {
    float ev = expf(vals[m] - gmax);
    vals[m] = ev;
    ls += ev;
  }
#pragma unroll
  for (int off = 32; off > 0; off >>= 1) ls += __shfl_down(ls, off);
  if (lane == 0) red[8 + wave] = ls;
  __syncthreads();
  const float inv = 1.0f / (red[8] + red[9] + red[10] + red[11]);
  for (int m = t; m < 2048; m += 256) {
    float v = vals[m] * inv;
    bf16_t h = f2b(v);
    adjH[(long)n * 2048 + m] = h;
    adjL[(long)n * 2048 + m] = f2b(v - b2f(h));
  }
}

// ------------- XT[b*64+i][m] = x[b][m][i], hi/lo planes --------------------
__global__ __launch_bounds__(256) void split_xt(const float* __restrict__ x,
                                                bf16_t* __restrict__ XTh,
                                                bf16_t* __restrict__ XTl) {
  __shared__ float tile[64][65];
  const int m0 = blockIdx.x * 64;
  const int b = blockIdx.y;
  const int tx = threadIdx.x & 63, ty = threadIdx.x >> 6;
  for (int r = ty; r < 64; r += 4)
    tile[r][tx] = x[(long)b * 131072 + (long)(m0 + r) * 64 + tx];
  __syncthreads();
  for (int r = ty; r < 64; r += 4) {
    float v = tile[tx][r];
    bf16_t h = f2b(v);
    long idx = (long)(b * 64 + r) * 2048 + m0 + tx;
    XTh[idx] = h;
    XTl[idx] = f2b(v - b2f(h));
  }
}

// ------------- generic fp32 transpose-split: out[c][r] = in[r][c] ----------
__global__ __launch_bounds__(256) void tsplit(const float* __restrict__ in,
                                              bf16_t* __restrict__ oH,
                                              bf16_t* __restrict__ oL, int R, int C) {
  __shared__ float tile[64][65];
  const int c0 = blockIdx.x * 64, r0 = blockIdx.y * 64;
  const int tx = threadIdx.x & 63, ty = threadIdx.x >> 6;
  for (int r = ty; r < 64; r += 4)
    tile[r][tx] = in[(long)(r0 + r) * C + c0 + tx];
  __syncthreads();
  for (int r = ty; r < 64; r += 4) {
    float v = tile[tx][r];
    bf16_t h = f2b(v);
    long idx = (long)(c0 + r) * R + r0 + tx;
    oH[idx] = h;
    oL[idx] = f2b(v - b2f(h));
  }
}

// ------------- permute w_pool (E,3,I,O) -> P[e][o*KI + k*I+i], fp32 --------
__global__ __launch_bounds__(256) void permute_pool(const float* __restrict__ wp,
                                                    float* __restrict__ P,
                                                    int KI, int I, int O) {
  const int g = blockIdx.x * 256 + threadIdx.x;
  const int per = KI * O;  // 24576
  const int e = g / per, rem = g % per;
  const int o = rem / KI, kk = rem % KI;
  const int k = kk / I, i = kk % I;
  P[g] = wp[(long)((e * 3 + k) * I + i) * O + o];
}

// ------------- W[n][c] = bf16(sum_e emb[n,e] * P[e][c]) — 96 MiB out -------
__global__ __launch_bounds__(256) void wgen(const float* __restrict__ P,
                                            const float* __restrict__ emb,
                                            bf16_t* __restrict__ W) {
  __shared__ float Ps[10 * 1024];
  __shared__ float es[160];
  const int c0 = blockIdx.x * 1024;
  const int n0 = blockIdx.y * 16;
  const int t = threadIdx.x;
  for (int g = t; g < 10240; g += 256) {
    int e = g >> 10, idx = g & 1023;
    Ps[g] = P[(long)e * 24576 + c0 + idx];
  }
  if (t < 160) es[t] = emb[n0 * 10 + t];
  __syncthreads();
  for (int nn = 0; nn < 16; ++nn) {
    float e0 = es[nn * 10 + 0], e1 = es[nn * 10 + 1], e2 = es[nn * 10 + 2],
          e3 = es[nn * 10 + 3], e4 = es[nn * 10 + 4], e5 = es[nn * 10 + 5],
          e6 = es[nn * 10 + 6], e7 = es[nn * 10 + 7], e8 = es[nn * 10 + 8],
          e9 = es[nn * 10 + 9];
#pragma unroll
    for (int q = 0; q < 4; ++q) {
      int idx = q * 256 + t;
      float v = e0 * Ps[idx] + e1 * Ps[1024 + idx] + e2 * Ps[2048 + idx] +
                e3 * Ps[3072 + idx] + e4 * Ps[4096 + idx] + e5 * Ps[5120 + idx] +
                e6 * Ps[6144 + idx] + e7 * Ps[7168 + idx] + e8 * Ps[8192 + idx] +
                e9 * Ps[9216 + idx];
      W[(long)(n0 + nn) * 24576 + c0 + idx] = f2b(v);
    }
  }
}

// ------------- fused multi-product GEMM v3 ---------------------------------
// 128(M)x64(N) tile, BK=64, XOR-swizzled LDS (chunk c of row r at slot
// c^(r&7); read slot (kh*4+quad)^(fr&7) -> balanced banks, 0 conflicts).
// Wave tile 32x64 (acc[2][4]) -> 0.75 KB LDS traffic/MFMA (was 1.0).
// C[i,j] = sum_k A[i,k]*B[j,k]; products Ah*Bh (+Ah*Bl if BLO) (+Al*Bh if ALO)
// grid (N/64, M/128), 256 threads.  Per-element MFMA order == v2 (bit-identical).
template <int ALO, int BLO>
__global__ __launch_bounds__(256) void fgemm(const bf16_t* __restrict__ Ah,
                                             const bf16_t* __restrict__ Al,
                                             const bf16_t* __restrict__ Bh,
                                             const bf16_t* __restrict__ Bl,
                                             float* __restrict__ Cf, int K, int ldc) {
  __shared__ __align__(16) bf16_t Ash[128 * 64];
  __shared__ __align__(16) bf16_t Asl[ALO ? 128 * 64 : 8];
  __shared__ __align__(16) bf16_t Bsh[64 * 64];
  __shared__ __align__(16) bf16_t Bsl[BLO ? 64 * 64 : 8];
  const int t = threadIdx.x;
  const int wave = t >> 6, lane = t & 63;
  const long m0 = (long)blockIdx.y * 128;
  const long n0 = (long)blockIdx.x * 64;
  // staging: thread t covers row (t>>3) within a 32-row call, swizzled chunk
  const int srow = t >> 3;                        // 0..31
  const int sc8 = ((t & 7) ^ (srow & 7)) << 3;    // source chunk offset (elems)
  const int fr = lane & 15;
  const int quad = lane >> 4;
  const int wm = wave * 32;
  char* lA = (char*)Ash + wave * 1024;
  char* lAl2 = (char*)Asl + wave * 1024;
  char* lB = (char*)Bsh + wave * 1024;
  char* lBl2 = (char*)Bsl + wave * 1024;
  f32x4 acc[2][4] = {};
  for (int k0 = 0; k0 < K; k0 += 64) {
#pragma unroll
    for (int q = 0; q < 4; ++q)
      gload_lds16(Ah + (m0 + q * 32 + srow) * K + k0 + sc8, lA + q * 4096);
#pragma unroll
    for (int q = 0; q < 2; ++q)
      gload_lds16(Bh + (n0 + q * 32 + srow) * K + k0 + sc8, lB + q * 4096);
    if (ALO)
#pragma unroll
      for (int q = 0; q < 4; ++q)
        gload_lds16(Al + (m0 + q * 32 + srow) * K + k0 + sc8, lAl2 + q * 4096);
    if (BLO)
#pragma unroll
      for (int q = 0; q < 2; ++q)
        gload_lds16(Bl + (n0 + q * 32 + srow) * K + k0 + sc8, lBl2 + q * 4096);
    __syncthreads();
#pragma unroll
    for (int kh = 0; kh < 2; ++kh) {
      const int cbase = kh * 4 + quad;
      bf16x8 ah[2], bh[4];
#pragma unroll
      for (int i = 0; i < 2; ++i) {
        const int r = wm + i * 16 + fr;
        ah[i] = *(const bf16x8*)(Ash + r * 64 + ((cbase ^ (fr & 7)) << 3));
      }
#pragma unroll
      for (int j = 0; j < 4; ++j) {
        const int r = j * 16 + fr;
        bh[j] = *(const bf16x8*)(Bsh + r * 64 + ((cbase ^ (fr & 7)) << 3));
      }
#pragma unroll
      for (int i = 0; i < 2; ++i)
#pragma unroll
        for (int j = 0; j < 4; ++j)
          acc[i][j] = __builtin_amdgcn_mfma_f32_16x16x32_bf16(ah[i], bh[j], acc[i][j], 0, 0, 0);
      if (BLO) {
        bf16x8 bl[4];
#pragma unroll
        for (int j = 0; j < 4; ++j) {
          const int r = j * 16 + fr;
          bl[j] = *(const bf16x8*)(Bsl + r * 64 + ((cbase ^ (fr & 7)) << 3));
        }
#pragma unroll
        for (int i = 0; i < 2; ++i)
#pragma unroll
          for (int j = 0; j < 4; ++j)
            acc[i][j] = __builtin_amdgcn_mfma_f32_16x16x32_bf16(ah[i], bl[j], acc[i][j], 0, 0, 0);
      }
      if (ALO) {
        bf16x8 al[2];
#pragma unroll
        for (int i = 0; i < 2; ++i) {
          const int r = wm + i * 16 + fr;
          al[i] = *(const bf16x8*)(Asl + r * 64 + ((cbase ^ (fr & 7)) << 3));
        }
#pragma unroll
        for (int i = 0; i < 2; ++i)
#pragma unroll
          for (int j = 0; j < 4; ++j)
            acc[i][j] = __builtin_amdgcn_mfma_f32_16x16x32_bf16(al[i], bh[j], acc[i][j], 0, 0, 0);
      }
    }
    __syncthreads();
  }
  const int crow = quad * 4, ccol = fr;
#pragma unroll
  for (int i = 0; i < 2; ++i)
#pragma unroll
    for (int j = 0; j < 4; ++j)
#pragma unroll
      for (int r = 0; r < 4; ++r) {
        long gm = m0 + wm + i * 16 + crow + r;
        long gn = n0 + j * 16 + ccol;
        Cf[gm * ldc + gn] = acc[i][j][r];
      }
}

// ------------- gate (o-split): (32x192)@W_half(192x64)+bias, sigmoid -------
// grid 4096: block = (n, oh).  A = [x | Xg1 | 2*Xg2raw - x] fp32 -> hi/lo in
// LDS (25.6 KB).  W streamed from materialized Wg (global, no LDS stage).
__global__ __launch_bounds__(256) void gate_kernel(
    const float* __restrict__ x, const float* __restrict__ Xg1f,
    const float* __restrict__ Xg2r, const bf16_t* __restrict__ Wg,
    const float* __restrict__ bpool, const float* __restrict__ emb,
    float* __restrict__ Zf, bf16_t* __restrict__ rb) {
  __shared__ __align__(16) bf16_t Ahi[32 * 200];
  __shared__ __align__(16) bf16_t Alo[32 * 200];
  const int n = blockIdx.x >> 1;
  const int oh = blockIdx.x & 1;
  const int t = threadIdx.x;
  float en[10];
#pragma unroll
  for (int e = 0; e < 10; ++e) en[e] = emb[n * 10 + e];
  {
    const int b = t >> 3, i8 = (t & 7) * 8;
    const float* s0 = x + (long)b * 131072 + (long)n * 64 + i8;
    const float* s1 = Xg1f + (long)n * 2048 + b * 64 + i8;
    const float* s2 = Xg2r + (long)n * 2048 + b * 64 + i8;
    float v0[8], v1[8], v2[8];
#pragma unroll
    for (int j = 0; j < 8; ++j) v0[j] = s0[j];
#pragma unroll
    for (int j = 0; j < 8; ++j) v1[j] = s1[j];
#pragma unroll
    for (int j = 0; j < 8; ++j) v2[j] = 2.0f * s2[j] - v0[j];
    union { uint4 u; bf16_t h[8]; } th, tl;
#pragma unroll
    for (int j = 0; j < 8; ++j) {
      bf16_t h = f2b(v0[j]); th.h[j] = h; tl.h[j] = f2b(v0[j] - b2f(h));
    }
    *(uint4*)(Ahi + b * 200 + i8) = th.u;
    *(uint4*)(Alo + b * 200 + i8) = tl.u;
#pragma unroll
    for (int j = 0; j < 8; ++j) {
      bf16_t h = f2b(v1[j]); th.h[j] = h; tl.h[j] = f2b(v1[j] - b2f(h));
    }
    *(uint4*)(Ahi + b * 200 + 64 + i8) = th.u;
    *(uint4*)(Alo + b * 200 + 64 + i8) = tl.u;
#pragma unroll
    for (int j = 0; j < 8; ++j) {
      bf16_t h = f2b(v2[j]); th.h[j] = h; tl.h[j] = f2b(v2[j] - b2f(h));
    }
    *(uint4*)(Ahi + b * 200 + 128 + i8) = th.u;
    *(uint4*)(Alo + b * 200 + 128 + i8) = tl.u;
  }
  __syncthreads();
  const int wave = t >> 6, lane = t & 63;
  const int ob = wave * 16;
  const int fr = lane & 15, qk = (lane >> 4) * 8;
  const bf16_t* Wp = Wg + (long)n * 24576 + (long)oh * 12288 + (ob + fr) * 192 + qk;
  f32x4 acc[2] = {};
#pragma unroll
  for (int k0 = 0; k0 < 192; k0 += 32) {
    bf16x8 bh = *(const bf16x8*)(Wp + k0);
    bf16x8 a0h = *(const bf16x8*)(Ahi + fr * 200 + k0 + qk);
    bf16x8 a1h = *(const bf16x8*)(Ahi + (16 + fr) * 200 + k0 + qk);
    bf16x8 a0l = *(const bf16x8*)(Alo + fr * 200 + k0 + qk);
    bf16x8 a1l = *(const bf16x8*)(Alo + (16 + fr) * 200 + k0 + qk);
    acc[0] = __builtin_amdgcn_mfma_f32_16x16x32_bf16(a0h, bh, acc[0], 0, 0, 0);
    acc[0] = __builtin_amdgcn_mfma_f32_16x16x32_bf16(a0l, bh, acc[0], 0, 0, 0);
    acc[1] = __builtin_amdgcn_mfma_f32_16x16x32_bf16(a1h, bh, acc[1], 0, 0, 0);
    acc[1] = __builtin_amdgcn_mfma_f32_16x16x32_bf16(a1l, bh, acc[1], 0, 0, 0);
  }
  const int quad = lane >> 4;
  const int o_loc = ob + fr;
  const int o_glob = oh * 64 + o_loc;
  float bias = 0.f;
#pragma unroll
  for (int e = 0; e < 10; ++e) bias += en[e] * bpool[e * 128 + o_glob];
#pragma unroll
  for (int i2 = 0; i2 < 2; ++i2)
#pragma unroll
    for (int r = 0; r < 4; ++r) {
      const int b = i2 * 16 + quad * 4 + r;
      float v = acc[i2][r] + bias;
      v = 1.0f / (1.0f + expf(-v));
      if (oh == 0)
        Zf[(long)n * 2048 + b * 64 + o_loc] = v;
      else
        rb[(long)n * 2048 + b * 64 + o_loc] = f2b(v);
    }
}

// ------------- update: (32x384)@W_half(384x32), tanh, GRU blend ------------
// grid 4096: block = (n, oh).  A = [x|z | Xg1|Cgz1 | 2*Xg2r-x | 2*Cgz2r-z]
// fp32 -> hi/lo in LDS (49 KB).  W streamed from global Wu.
__global__ __launch_bounds__(256) void update_kernel(
    const float* __restrict__ x, const float* __restrict__ Zf,
    const float* __restrict__ Xg1f, const float* __restrict__ Cgz1f,
    const float* __restrict__ Xg2r, const float* __restrict__ Cgz2r,
    const bf16_t* __restrict__ Wu, const float* __restrict__ bpool,
    const float* __restrict__ emb, const bf16_t* __restrict__ rb,
    float* __restrict__ out) {
  __shared__ __align__(16) bf16_t Ahi[32 * 392];
  __shared__ __align__(16) bf16_t Alo[32 * 392];
  const int n = blockIdx.x >> 1;
  const int oh = blockIdx.x & 1;
  const int t = threadIdx.x;
  float en[10];
#pragma unroll
  for (int e = 0; e < 10; ++e) en[e] = emb[n * 10 + e];
#pragma unroll
  for (int r = 0; r < 2; ++r) {
    const int c = r * 2048 + t * 8;  // (b, j) over 32 x 128
    const int b = c >> 7, j = c & 127;
    const int lo64 = j & 63;
    const float* s0 = (j < 64) ? (x + (long)b * 131072 + (long)n * 64 + lo64)
                               : (Zf + (long)n * 2048 + b * 64 + lo64);
    const float* s1 = (j < 64) ? (Xg1f + (long)n * 2048 + b * 64 + lo64)
                               : (Cgz1f + (long)n * 2048 + b * 64 + lo64);
    const float* s2 = (j < 64) ? (Xg2r + (long)n * 2048 + b * 64 + lo64)
                               : (Cgz2r + (long)n * 2048 + b * 64 + lo64);
    float v0[8], v1[8], v2[8];
#pragma unroll
    for (int q = 0; q < 8; ++q) v0[q] = s0[q];
#pragma unroll
    for (int q = 0; q < 8; ++q) v1[q] = s1[q];
#pragma unroll
    for (int q = 0; q < 8; ++q) v2[q] = 2.0f * s2[q] - v0[q];
    union { uint4 u; bf16_t h[8]; } th, tl;
#pragma unroll
    for (int q = 0; q < 8; ++q) {
      bf16_t h = f2b(v0[q]); th.h[q] = h; tl.h[q] = f2b(v0[q] - b2f(h));
    }
    *(uint4*)(Ahi + b * 392 + j) = th.u;
    *(uint4*)(Alo + b * 392 + j) = tl.u;
#pragma unroll
    for (int q = 0; q < 8; ++q) {
      bf16_t h = f2b(v1[q]); th.h[q] = h; tl.h[q] = f2b(v1[q] - b2f(h));
    }
    *(uint4*)(Ahi + b * 392 + 128 + j) = th.u;
    *(uint4*)(Alo + b * 392 + 128 + j) = tl.u;
#pragma unroll
    for (int q = 0; q < 8; ++q) {
      bf16_t h = f2b(v2[q]); th.h[q] = h; tl.h[q] = f2b(v2[q] - b2f(h));
    }
    *(uint4*)(Ahi + b * 392 + 256 + j) = th.u;
    *(uint4*)(Alo + b * 392 + 256 + j) = tl.u;
  }
  __syncthreads();
  const int wave = t >> 6, lane = t & 63;
  const int mh = (wave >> 1) * 16;
  const int ob = (wave & 1) * 16;
  const int fr = lane & 15, qk = (lane >> 4) * 8;
  const bf16_t* Wp = Wu + (long)n * 24576 + (long)oh * 12288 + (ob + fr) * 384 + qk;
  f32x4 acc = {};
#pragma unroll
  for (int k0 = 0; k0 < 384; k0 += 32) {
    bf16x8 bh = *(const bf16x8*)(Wp + k0);
    bf16x8 ah = *(const bf16x8*)(Ahi + (mh + fr) * 392 + k0 + qk);
    bf16x8 al = *(const bf16x8*)(Alo + (mh + fr) * 392 + k0 + qk);
    acc = __builtin_amdgcn_mfma_f32_16x16x32_bf16(ah, bh, acc, 0, 0, 0);
    acc = __builtin_amdgcn_mfma_f32_16x16x32_bf16(al, bh, acc, 0, 0, 0);
  }
  const int quad = lane >> 4;
  const int og = oh * 32 + ob + fr;
  float bias = 0.f;
#pragma unroll
  for (int e = 0; e < 10; ++e) bias += en[e] * bpool[e * 64 + og];
#pragma unroll
  for (int r = 0; r < 4; ++r) {
    const int b = mh + quad * 4 + r;
    float hc = tanhf(acc[r] + bias);
    float rr = b2f(rb[(long)n * 2048 + b * 64 + og]);
    float xv = x[(long)b * 131072 + (long)n * 64 + og];
    out[(long)b * 131072 + (long)n * 64 + og] = rr * xv + (1.0f - rr) * hc;
  }
}

extern "C" void kernel_launch(void* const* d_in, const int* in_sizes, int n_in,
                              void* d_out, int out_size, void* d_ws, size_t ws_size,
                              hipStream_t stream) {
  (void)in_sizes; (void)n_in; (void)out_size;
  const float* x   = (const float*)d_in[0];
  const float* emb = (const float*)d_in[2];
  const float* gwp = (const float*)d_in[3];
  const float* gbp = (const float*)d_in[4];
  const float* uwp = (const float*)d_in[5];
  const float* ubp = (const float*)d_in[6];
  float* out = (float*)d_out;
  char* ws = (char*)d_ws;

  // high-water 194,904,064 B (round-9-proven). Guard:
  if (ws_size < 194904064ull) return;

  // ---- live-range-checked layout (W buffers are 96 MiB EACH) ----
  float*  Xg1f  = (float*)(ws);                  // 16 MiB [0, 16.8M)   alive: fgemm1 -> update
  float*  Xg2r  = (float*)(ws + 16777216);       // 16 MiB [16.8,33.6M) alive: fgemm2 -> update
  float*  Zf    = (float*)(ws + 33554432);       // 16 MiB [33.6,50.3M) alive: gate -> update
  bf16_t* rb    = (bf16_t*)(ws + 50331648);      //  8 MiB [50.3,58.7M) alive: gate -> update
  float*  Pg    = (float*)(ws + 58720256);       // 983040 [58.7,59.7M) dead after wgen#1
  float*  Pu    = (float*)(ws + 59703296);       // 983040 [59.7,60.7M) dead after wgen#2
  // Wu 96 MiB [60.7M, 161.3M): born at wgen#2, AFTER adj/S/Wg-head are dead.
  bf16_t* Wu    = (bf16_t*)(ws + 60686336);
  //   overlays (alive adj_softmax -> last fgemm):
  bf16_t* adjH  = (bf16_t*)(ws + 60686336);      //  8 MiB
  bf16_t* adjL  = (bf16_t*)(ws + 69074944);      //  8 MiB
  char*   S     = ws + 77463552;                 // 16 MiB transpose scratch
  // Wg 96 MiB [94.2M, 194.9M): born wgen#1, dead after gate.
  bf16_t* Wg    = (bf16_t*)(ws + 94240768);
  //   tail overlays (born after gate -> alive into update):
  float*  Cgz1f = (float*)(ws + 161349632);      // 16 MiB [161.3,178.1M)
  float*  Cgz2r = (float*)(ws + 178126848);      // 16 MiB [178.1,194.9M)
  bf16_t* Sh    = (bf16_t*)S;                    // hi plane (8 MiB)
  bf16_t* Sl    = (bf16_t*)(S + 8388608);        // lo plane (8 MiB)

  permute_pool<<<960, 256, 0, stream>>>(gwp, Pg, 192, 64, 128);
  permute_pool<<<960, 256, 0, stream>>>(uwp, Pu, 384, 128, 64);
  wgen<<<dim3(24, 128), 256, 0, stream>>>(Pg, emb, Wg);  // materialize gate W (96 MiB)
  adj_softmax<<<2048, 256, 0, stream>>>(emb, adjH, adjL);
  split_xt<<<dim3(32, 32), 256, 0, stream>>>(x, Sh, Sl);

  // Xg1 = A@x (2-prod) ; Xg2r = A@Xg1 raw (3-prod); consumers apply 2v-x
  fgemm<0, 1><<<dim3(32, 16), 256, 0, stream>>>(adjH, nullptr, Sh, Sl, Xg1f, 2048, 2048);
  tsplit<<<dim3(32, 32), 256, 0, stream>>>(Xg1f, Sh, Sl, 2048, 2048);
  fgemm<1, 1><<<dim3(32, 16), 256, 0, stream>>>(adjH, adjL, Sh, Sl, Xg2r, 2048, 2048);

  gate_kernel<<<4096, 256, 0, stream>>>(x, Xg1f, Xg2r, Wg, gbp, emb, Zf, rb);
  // Wg dead from here; its tail now hosts Cgz1f/Cgz2r.

  // Cgz1 = A@z (2-prod) ; Cgz2r = A@Cgz1 raw (3-prod); update applies 2v-z
  tsplit<<<dim3(32, 32), 256, 0, stream>>>(Zf, Sh, Sl, 2048, 2048);
  fgemm<0, 1><<<dim3(32, 16), 256, 0, stream>>>(adjH, nullptr, Sh, Sl, Cgz1f, 2048, 2048);
  tsplit<<<dim3(32, 32), 256, 0, stream>>>(Cgz1f, Sh, Sl, 2048, 2048);
  fgemm<1, 1><<<dim3(32, 16), 256, 0, stream>>>(adjH, adjL, Sh, Sl, Cgz2r, 2048, 2048);
  // adj + S + Wg-head dead from here; Wu may be materialized over them.

  wgen<<<dim3(24, 128), 256, 0, stream>>>(Pu, emb, Wu);  // materialize update W (96 MiB)
  update_kernel<<<4096, 256, 0, stream>>>(x, Zf, Xg1f, Cgz1f, Xg2r, Cgz2r, Wu,
                                          ubp, emb, rb, out);
}

// Round 12
// 446.867 us; speedup vs baseline: 1.7080x; 1.0404x over previous
//
#include <hip/hip_runtime.h>
#include <hip/hip_bf16.h>

typedef __hip_bfloat16 bf16_t;
typedef float f32x4 __attribute__((ext_vector_type(4)));
typedef __bf16 bf16x8 __attribute__((ext_vector_type(8)));

#define AS1 __attribute__((address_space(1)))
#define AS3 __attribute__((address_space(3)))

__device__ __forceinline__ void gload_lds16(const void* g, void* l) {
  __builtin_amdgcn_global_load_lds((const AS1 void*)g, (AS3 void*)l, 16, 0, 0);
}

__device__ __forceinline__ bf16_t f2b(float v) { return __float2bfloat16(v); }
__device__ __forceinline__ float b2f(bf16_t v) { return __bfloat162float(v); }

// ------------- adj = softmax(relu(E E^T), axis=1), hi/lo bf16 planes -------
__global__ __launch_bounds__(256) void adj_softmax(const float* __restrict__ emb,
                                                   bf16_t* __restrict__ adjH,
                                                   bf16_t* __restrict__ adjL) {
  __shared__ float vals[2048];
  __shared__ float red[16];
  const int n = blockIdx.x;
  const int t = threadIdx.x;
  const int lane = t & 63, wave = t >> 6;
  float en[10];
#pragma unroll
  for (int e = 0; e < 10; ++e) en[e] = emb[n * 10 + e];
  float lm = 0.0f;
  for (int m = t; m < 2048; m += 256) {
    const float* em = emb + m * 10;
    float d = 0.f;
#pragma unroll
    for (int e = 0; e < 10; ++e) d += en[e] * em[e];
    d = fmaxf(d, 0.0f);
    vals[m] = d;
    lm = fmaxf(lm, d);
  }
#pragma unroll
  for (int off = 32; off > 0; off >>= 1) lm = fmaxf(lm, __shfl_down(lm, off));
  if (lane == 0) red[wave] = lm;
  __syncthreads();
  const float gmax = fmaxf(fmaxf(red[0], red[1]), fmaxf(red[2], red[3]));
  float ls = 0.f;
  for (int m = t; m < 2048; m += 256) {
    float ev = expf(vals[m] - gmax);
    vals[m] = ev;
    ls += ev;
  }
#pragma unroll
  for (int off = 32; off > 0; off >>= 1) ls += __shfl_down(ls, off);
  if (lane == 0) red[8 + wave] = ls;
  __syncthreads();
  const float inv = 1.0f / (red[8] + red[9] + red[10] + red[11]);
  for (int m = t; m < 2048; m += 256) {
    float v = vals[m] * inv;
    bf16_t h = f2b(v);
    adjH[(long)n * 2048 + m] = h;
    adjL[(long)n * 2048 + m] = f2b(v - b2f(h));
  }
}

// ------------- XT[b*64+i][m] = x[b][m][i], hi/lo planes --------------------
__global__ __launch_bounds__(256) void split_xt(const float* __restrict__ x,
                                                bf16_t* __restrict__ XTh,
                                                bf16_t* __restrict__ XTl) {
  __shared__ float tile[64][65];
  const int m0 = blockIdx.x * 64;
  const int b = blockIdx.y;
  const int tx = threadIdx.x & 63, ty = threadIdx.x >> 6;
  for (int r = ty; r < 64; r += 4)
    tile[r][tx] = x[(long)b * 131072 + (long)(m0 + r) * 64 + tx];
  __syncthreads();
  for (int r = ty; r < 64; r += 4) {
    float v = tile[tx][r];
    bf16_t h = f2b(v);
    long idx = (long)(b * 64 + r) * 2048 + m0 + tx;
    XTh[idx] = h;
    XTl[idx] = f2b(v - b2f(h));
  }
}

// ------------- generic fp32 transpose-split: out[c][r] = in[r][c] ----------
__global__ __launch_bounds__(256) void tsplit(const float* __restrict__ in,
                                              bf16_t* __restrict__ oH,
                                              bf16_t* __restrict__ oL, int R, int C) {
  __shared__ float tile[64][65];
  const int c0 = blockIdx.x * 64, r0 = blockIdx.y * 64;
  const int tx = threadIdx.x & 63, ty = threadIdx.x >> 6;
  for (int r = ty; r < 64; r += 4)
    tile[r][tx] = in[(long)(r0 + r) * C + c0 + tx];
  __syncthreads();
  for (int r = ty; r < 64; r += 4) {
    float v = tile[tx][r];
    bf16_t h = f2b(v);
    long idx = (long)(c0 + r) * R + r0 + tx;
    oH[idx] = h;
    oL[idx] = f2b(v - b2f(h));
  }
}

// ------------- permute w_pool (E,3,I,O) -> P[e][o*KI + k*I+i], fp32 --------
__global__ __launch_bounds__(256) void permute_pool(const float* __restrict__ wp,
                                                    float* __restrict__ P,
                                                    int KI, int I, int O) {
  const int g = blockIdx.x * 256 + threadIdx.x;
  const int per = KI * O;  // 24576
  const int e = g / per, rem = g % per;
  const int o = rem / KI, kk = rem % KI;
  const int k = kk / I, i = kk % I;
  P[g] = wp[(long)((e * 3 + k) * I + i) * O + o];
}

// ------------- W[n][c] = bf16(sum_e emb[n,e] * P[e][c]) — 96 MiB out -------
__global__ __launch_bounds__(256) void wgen(const float* __restrict__ P,
                                            const float* __restrict__ emb,
                                            bf16_t* __restrict__ W) {
  __shared__ float Ps[10 * 1024];
  __shared__ float es[160];
  const int c0 = blockIdx.x * 1024;
  const int n0 = blockIdx.y * 16;
  const int t = threadIdx.x;
  for (int g = t; g < 10240; g += 256) {
    int e = g >> 10, idx = g & 1023;
    Ps[g] = P[(long)e * 24576 + c0 + idx];
  }
  if (t < 160) es[t] = emb[n0 * 10 + t];
  __syncthreads();
  for (int nn = 0; nn < 16; ++nn) {
    float e0 = es[nn * 10 + 0], e1 = es[nn * 10 + 1], e2 = es[nn * 10 + 2],
          e3 = es[nn * 10 + 3], e4 = es[nn * 10 + 4], e5 = es[nn * 10 + 5],
          e6 = es[nn * 10 + 6], e7 = es[nn * 10 + 7], e8 = es[nn * 10 + 8],
          e9 = es[nn * 10 + 9];
#pragma unroll
    for (int q = 0; q < 4; ++q) {
      int idx = q * 256 + t;
      float v = e0 * Ps[idx] + e1 * Ps[1024 + idx] + e2 * Ps[2048 + idx] +
                e3 * Ps[3072 + idx] + e4 * Ps[4096 + idx] + e5 * Ps[5120 + idx] +
                e6 * Ps[6144 + idx] + e7 * Ps[7168 + idx] + e8 * Ps[8192 + idx] +
                e9 * Ps[9216 + idx];
      W[(long)(n0 + nn) * 24576 + c0 + idx] = f2b(v);
    }
  }
}

// ------------- fused multi-product GEMM v3 ---------------------------------
// 128(M)x64(N) tile, BK=64, XOR-swizzled LDS.  (unchanged from round 11)
template <int ALO, int BLO>
__global__ __launch_bounds__(256) void fgemm(const bf16_t* __restrict__ Ah,
                                             const bf16_t* __restrict__ Al,
                                             const bf16_t* __restrict__ Bh,
                                             const bf16_t* __restrict__ Bl,
                                             float* __restrict__ Cf, int K, int ldc) {
  __shared__ __align__(16) bf16_t Ash[128 * 64];
  __shared__ __align__(16) bf16_t Asl[ALO ? 128 * 64 : 8];
  __shared__ __align__(16) bf16_t Bsh[64 * 64];
  __shared__ __align__(16) bf16_t Bsl[BLO ? 64 * 64 : 8];
  const int t = threadIdx.x;
  const int wave = t >> 6, lane = t & 63;
  const long m0 = (long)blockIdx.y * 128;
  const long n0 = (long)blockIdx.x * 64;
  const int srow = t >> 3;
  const int sc8 = ((t & 7) ^ (srow & 7)) << 3;
  const int fr = lane & 15;
  const int quad = lane >> 4;
  const int wm = wave * 32;
  char* lA = (char*)Ash + wave * 1024;
  char* lAl2 = (char*)Asl + wave * 1024;
  char* lB = (char*)Bsh + wave * 1024;
  char* lBl2 = (char*)Bsl + wave * 1024;
  f32x4 acc[2][4] = {};
  for (int k0 = 0; k0 < K; k0 += 64) {
#pragma unroll
    for (int q = 0; q < 4; ++q)
      gload_lds16(Ah + (m0 + q * 32 + srow) * K + k0 + sc8, lA + q * 4096);
#pragma unroll
    for (int q = 0; q < 2; ++q)
      gload_lds16(Bh + (n0 + q * 32 + srow) * K + k0 + sc8, lB + q * 4096);
    if (ALO)
#pragma unroll
      for (int q = 0; q < 4; ++q)
        gload_lds16(Al + (m0 + q * 32 + srow) * K + k0 + sc8, lAl2 + q * 4096);
    if (BLO)
#pragma unroll
      for (int q = 0; q < 2; ++q)
        gload_lds16(Bl + (n0 + q * 32 + srow) * K + k0 + sc8, lBl2 + q * 4096);
    __syncthreads();
#pragma unroll
    for (int kh = 0; kh < 2; ++kh) {
      const int cbase = kh * 4 + quad;
      bf16x8 ah[2], bh[4];
#pragma unroll
      for (int i = 0; i < 2; ++i) {
        const int r = wm + i * 16 + fr;
        ah[i] = *(const bf16x8*)(Ash + r * 64 + ((cbase ^ (fr & 7)) << 3));
      }
#pragma unroll
      for (int j = 0; j < 4; ++j) {
        const int r = j * 16 + fr;
        bh[j] = *(const bf16x8*)(Bsh + r * 64 + ((cbase ^ (fr & 7)) << 3));
      }
#pragma unroll
      for (int i = 0; i < 2; ++i)
#pragma unroll
        for (int j = 0; j < 4; ++j)
          acc[i][j] = __builtin_amdgcn_mfma_f32_16x16x32_bf16(ah[i], bh[j], acc[i][j], 0, 0, 0);
      if (BLO) {
        bf16x8 bl[4];
#pragma unroll
        for (int j = 0; j < 4; ++j) {
          const int r = j * 16 + fr;
          bl[j] = *(const bf16x8*)(Bsl + r * 64 + ((cbase ^ (fr & 7)) << 3));
        }
#pragma unroll
        for (int i = 0; i < 2; ++i)
#pragma unroll
          for (int j = 0; j < 4; ++j)
            acc[i][j] = __builtin_amdgcn_mfma_f32_16x16x32_bf16(ah[i], bl[j], acc[i][j], 0, 0, 0);
      }
      if (ALO) {
        bf16x8 al[2];
#pragma unroll
        for (int i = 0; i < 2; ++i) {
          const int r = wm + i * 16 + fr;
          al[i] = *(const bf16x8*)(Asl + r * 64 + ((cbase ^ (fr & 7)) << 3));
        }
#pragma unroll
        for (int i = 0; i < 2; ++i)
#pragma unroll
          for (int j = 0; j < 4; ++j)
            acc[i][j] = __builtin_amdgcn_mfma_f32_16x16x32_bf16(al[i], bh[j], acc[i][j], 0, 0, 0);
      }
    }
    __syncthreads();
  }
  const int crow = quad * 4, ccol = fr;
#pragma unroll
  for (int i = 0; i < 2; ++i)
#pragma unroll
    for (int j = 0; j < 4; ++j)
#pragma unroll
      for (int r = 0; r < 4; ++r) {
        long gm = m0 + wm + i * 16 + crow + r;
        long gn = n0 + j * 16 + ccol;
        Cf[gm * ldc + gn] = acc[i][j][r];
      }
}

// ------------- gate: one block per node n (grid 2048) ----------------------
// (32x192)@W_n(192x128)+bias, sigmoid.  A staged/converted ONCE per node.
// Waves: ob = wave*32 (128 o total).  W streamed from materialized Wg.
__global__ __launch_bounds__(256) void gate_kernel(
    const float* __restrict__ x, const float* __restrict__ Xg1f,
    const float* __restrict__ Xg2r, const bf16_t* __restrict__ Wg,
    const float* __restrict__ bpool, const float* __restrict__ emb,
    float* __restrict__ Zf, bf16_t* __restrict__ rb) {
  __shared__ __align__(16) bf16_t Ahi[32 * 200];
  __shared__ __align__(16) bf16_t Alo[32 * 200];
  const int n = blockIdx.x;
  const int t = threadIdx.x;
  float en[10];
#pragma unroll
  for (int e = 0; e < 10; ++e) en[e] = emb[n * 10 + e];
  {
    const int b = t >> 3, i8 = (t & 7) * 8;
    const float* s0 = x + (long)b * 131072 + (long)n * 64 + i8;
    const float* s1 = Xg1f + (long)n * 2048 + b * 64 + i8;
    const float* s2 = Xg2r + (long)n * 2048 + b * 64 + i8;
    float v0[8], v1[8], v2[8];
#pragma unroll
    for (int j = 0; j < 8; ++j) v0[j] = s0[j];
#pragma unroll
    for (int j = 0; j < 8; ++j) v1[j] = s1[j];
#pragma unroll
    for (int j = 0; j < 8; ++j) v2[j] = 2.0f * s2[j] - v0[j];
    union { uint4 u; bf16_t h[8]; } th, tl;
#pragma unroll
    for (int j = 0; j < 8; ++j) {
      bf16_t h = f2b(v0[j]); th.h[j] = h; tl.h[j] = f2b(v0[j] - b2f(h));
    }
    *(uint4*)(Ahi + b * 200 + i8) = th.u;
    *(uint4*)(Alo + b * 200 + i8) = tl.u;
#pragma unroll
    for (int j = 0; j < 8; ++j) {
      bf16_t h = f2b(v1[j]); th.h[j] = h; tl.h[j] = f2b(v1[j] - b2f(h));
    }
    *(uint4*)(Ahi + b * 200 + 64 + i8) = th.u;
    *(uint4*)(Alo + b * 200 + 64 + i8) = tl.u;
#pragma unroll
    for (int j = 0; j < 8; ++j) {
      bf16_t h = f2b(v2[j]); th.h[j] = h; tl.h[j] = f2b(v2[j] - b2f(h));
    }
    *(uint4*)(Ahi + b * 200 + 128 + i8) = th.u;
    *(uint4*)(Alo + b * 200 + 128 + i8) = tl.u;
  }
  __syncthreads();
  const int wave = t >> 6, lane = t & 63;
  const int ob = wave * 32;
  const int fr = lane & 15, qk = (lane >> 4) * 8;
  const bf16_t* Wp0 = Wg + (long)n * 24576 + (ob + fr) * 192 + qk;
  const bf16_t* Wp1 = Wp0 + 16 * 192;
  f32x4 acc[2][2] = {};
#pragma unroll
  for (int k0 = 0; k0 < 192; k0 += 32) {
    bf16x8 b0 = *(const bf16x8*)(Wp0 + k0);
    bf16x8 b1 = *(const bf16x8*)(Wp1 + k0);
    bf16x8 a0h = *(const bf16x8*)(Ahi + fr * 200 + k0 + qk);
    bf16x8 a1h = *(const bf16x8*)(Ahi + (16 + fr) * 200 + k0 + qk);
    bf16x8 a0l = *(const bf16x8*)(Alo + fr * 200 + k0 + qk);
    bf16x8 a1l = *(const bf16x8*)(Alo + (16 + fr) * 200 + k0 + qk);
    acc[0][0] = __builtin_amdgcn_mfma_f32_16x16x32_bf16(a0h, b0, acc[0][0], 0, 0, 0);
    acc[0][0] = __builtin_amdgcn_mfma_f32_16x16x32_bf16(a0l, b0, acc[0][0], 0, 0, 0);
    acc[1][0] = __builtin_amdgcn_mfma_f32_16x16x32_bf16(a1h, b0, acc[1][0], 0, 0, 0);
    acc[1][0] = __builtin_amdgcn_mfma_f32_16x16x32_bf16(a1l, b0, acc[1][0], 0, 0, 0);
    acc[0][1] = __builtin_amdgcn_mfma_f32_16x16x32_bf16(a0h, b1, acc[0][1], 0, 0, 0);
    acc[0][1] = __builtin_amdgcn_mfma_f32_16x16x32_bf16(a0l, b1, acc[0][1], 0, 0, 0);
    acc[1][1] = __builtin_amdgcn_mfma_f32_16x16x32_bf16(a1h, b1, acc[1][1], 0, 0, 0);
    acc[1][1] = __builtin_amdgcn_mfma_f32_16x16x32_bf16(a1l, b1, acc[1][1], 0, 0, 0);
  }
  const int quad = lane >> 4;
#pragma unroll
  for (int j = 0; j < 2; ++j) {
    const int o = ob + j * 16 + fr;   // 0..127
    float bias = 0.f;
#pragma unroll
    for (int e = 0; e < 10; ++e) bias += en[e] * bpool[e * 128 + o];
#pragma unroll
    for (int i2 = 0; i2 < 2; ++i2)
#pragma unroll
      for (int r = 0; r < 4; ++r) {
        const int b = i2 * 16 + quad * 4 + r;
        float v = acc[i2][j][r] + bias;
        v = 1.0f / (1.0f + expf(-v));
        if (o < 64)
          Zf[(long)n * 2048 + b * 64 + o] = v;
        else
          rb[(long)n * 2048 + b * 64 + (o - 64)] = f2b(v);
      }
  }
}

// ------------- update: one block per node n (grid 2048) --------------------
// (32x384)@W_n(384x64), tanh, GRU blend.  A staged ONCE per node.
// Waves: ob = wave*16 (64 o); each wave covers both m-halves (acc[2]).
__global__ __launch_bounds__(256) void update_kernel(
    const float* __restrict__ x, const float* __restrict__ Zf,
    const float* __restrict__ Xg1f, const float* __restrict__ Cgz1f,
    const float* __restrict__ Xg2r, const float* __restrict__ Cgz2r,
    const bf16_t* __restrict__ Wu, const float* __restrict__ bpool,
    const float* __restrict__ emb, const bf16_t* __restrict__ rb,
    float* __restrict__ out) {
  __shared__ __align__(16) bf16_t Ahi[32 * 392];
  __shared__ __align__(16) bf16_t Alo[32 * 392];
  const int n = blockIdx.x;
  const int t = threadIdx.x;
  float en[10];
#pragma unroll
  for (int e = 0; e < 10; ++e) en[e] = emb[n * 10 + e];
#pragma unroll
  for (int r = 0; r < 2; ++r) {
    const int c = r * 2048 + t * 8;  // (b, j) over 32 x 128
    const int b = c >> 7, j = c & 127;
    const int lo64 = j & 63;
    const float* s0 = (j < 64) ? (x + (long)b * 131072 + (long)n * 64 + lo64)
                               : (Zf + (long)n * 2048 + b * 64 + lo64);
    const float* s1 = (j < 64) ? (Xg1f + (long)n * 2048 + b * 64 + lo64)
                               : (Cgz1f + (long)n * 2048 + b * 64 + lo64);
    const float* s2 = (j < 64) ? (Xg2r + (long)n * 2048 + b * 64 + lo64)
                               : (Cgz2r + (long)n * 2048 + b * 64 + lo64);
    float v0[8], v1[8], v2[8];
#pragma unroll
    for (int q = 0; q < 8; ++q) v0[q] = s0[q];
#pragma unroll
    for (int q = 0; q < 8; ++q) v1[q] = s1[q];
#pragma unroll
    for (int q = 0; q < 8; ++q) v2[q] = 2.0f * s2[q] - v0[q];
    union { uint4 u; bf16_t h[8]; } th, tl;
#pragma unroll
    for (int q = 0; q < 8; ++q) {
      bf16_t h = f2b(v0[q]); th.h[q] = h; tl.h[q] = f2b(v0[q] - b2f(h));
    }
    *(uint4*)(Ahi + b * 392 + j) = th.u;
    *(uint4*)(Alo + b * 392 + j) = tl.u;
#pragma unroll
    for (int q = 0; q < 8; ++q) {
      bf16_t h = f2b(v1[q]); th.h[q] = h; tl.h[q] = f2b(v1[q] - b2f(h));
    }
    *(uint4*)(Ahi + b * 392 + 128 + j) = th.u;
    *(uint4*)(Alo + b * 392 + 128 + j) = tl.u;
#pragma unroll
    for (int q = 0; q < 8; ++q) {
      bf16_t h = f2b(v2[q]); th.h[q] = h; tl.h[q] = f2b(v2[q] - b2f(h));
    }
    *(uint4*)(Ahi + b * 392 + 256 + j) = th.u;
    *(uint4*)(Alo + b * 392 + 256 + j) = tl.u;
  }
  __syncthreads();
  const int wave = t >> 6, lane = t & 63;
  const int ob = wave * 16;            // 64 o across 4 waves
  const int fr = lane & 15, qk = (lane >> 4) * 8;
  const bf16_t* Wp = Wu + (long)n * 24576 + (ob + fr) * 384 + qk;
  f32x4 acc[2] = {};
#pragma unroll
  for (int k0 = 0; k0 < 384; k0 += 32) {
    bf16x8 bh = *(const bf16x8*)(Wp + k0);
    bf16x8 a0h = *(const bf16x8*)(Ahi + fr * 392 + k0 + qk);
    bf16x8 a1h = *(const bf16x8*)(Ahi + (16 + fr) * 392 + k0 + qk);
    bf16x8 a0l = *(const bf16x8*)(Alo + fr * 392 + k0 + qk);
    bf16x8 a1l = *(const bf16x8*)(Alo + (16 + fr) * 392 + k0 + qk);
    acc[0] = __builtin_amdgcn_mfma_f32_16x16x32_bf16(a0h, bh, acc[0], 0, 0, 0);
    acc[0] = __builtin_amdgcn_mfma_f32_16x16x32_bf16(a0l, bh, acc[0], 0, 0, 0);
    acc[1] = __builtin_amdgcn_mfma_f32_16x16x32_bf16(a1h, bh, acc[1], 0, 0, 0);
    acc[1] = __builtin_amdgcn_mfma_f32_16x16x32_bf16(a1l, bh, acc[1], 0, 0, 0);
  }
  const int quad = lane >> 4;
  const int og = ob + fr;
  float bias = 0.f;
#pragma unroll
  for (int e = 0; e < 10; ++e) bias += en[e] * bpool[e * 64 + og];
#pragma unroll
  for (int i2 = 0; i2 < 2; ++i2)
#pragma unroll
    for (int r = 0; r < 4; ++r) {
      const int b = i2 * 16 + quad * 4 + r;
      float hc = tanhf(acc[i2][r] + bias);
      float rr = b2f(rb[(long)n * 2048 + b * 64 + og]);
      float xv = x[(long)b * 131072 + (long)n * 64 + og];
      out[(long)b * 131072 + (long)n * 64 + og] = rr * xv + (1.0f - rr) * hc;
    }
}

extern "C" void kernel_launch(void* const* d_in, const int* in_sizes, int n_in,
                              void* d_out, int out_size, void* d_ws, size_t ws_size,
                              hipStream_t stream) {
  (void)in_sizes; (void)n_in; (void)out_size;
  const float* x   = (const float*)d_in[0];
  const float* emb = (const float*)d_in[2];
  const float* gwp = (const float*)d_in[3];
  const float* gbp = (const float*)d_in[4];
  const float* uwp = (const float*)d_in[5];
  const float* ubp = (const float*)d_in[6];
  float* out = (float*)d_out;
  char* ws = (char*)d_ws;

  // high-water 194,904,064 B (round-11-proven). Guard:
  if (ws_size < 194904064ull) return;

  // ---- live-range-checked layout (W buffers are 96 MiB EACH) ----
  float*  Xg1f  = (float*)(ws);                  // 16 MiB
  float*  Xg2r  = (float*)(ws + 16777216);       // 16 MiB
  float*  Zf    = (float*)(ws + 33554432);       // 16 MiB
  bf16_t* rb    = (bf16_t*)(ws + 50331648);      //  8 MiB
  float*  Pg    = (float*)(ws + 58720256);       // 983040
  float*  Pu    = (float*)(ws + 59703296);       // 983040
  bf16_t* Wu    = (bf16_t*)(ws + 60686336);      // 96 MiB (after adj/S dead)
  bf16_t* adjH  = (bf16_t*)(ws + 60686336);      //  8 MiB (overlay)
  bf16_t* adjL  = (bf16_t*)(ws + 69074944);      //  8 MiB
  char*   S     = ws + 77463552;                 // 16 MiB scratch
  bf16_t* Wg    = (bf16_t*)(ws + 94240768);      // 96 MiB (dead after gate)
  float*  Cgz1f = (float*)(ws + 161349632);      // 16 MiB (Wg tail, post-gate)
  float*  Cgz2r = (float*)(ws + 178126848);      // 16 MiB
  bf16_t* Sh    = (bf16_t*)S;
  bf16_t* Sl    = (bf16_t*)(S + 8388608);

  permute_pool<<<960, 256, 0, stream>>>(gwp, Pg, 192, 64, 128);
  permute_pool<<<960, 256, 0, stream>>>(uwp, Pu, 384, 128, 64);
  wgen<<<dim3(24, 128), 256, 0, stream>>>(Pg, emb, Wg);
  adj_softmax<<<2048, 256, 0, stream>>>(emb, adjH, adjL);
  split_xt<<<dim3(32, 32), 256, 0, stream>>>(x, Sh, Sl);

  fgemm<0, 1><<<dim3(32, 16), 256, 0, stream>>>(adjH, nullptr, Sh, Sl, Xg1f, 2048, 2048);
  tsplit<<<dim3(32, 32), 256, 0, stream>>>(Xg1f, Sh, Sl, 2048, 2048);
  fgemm<1, 1><<<dim3(32, 16), 256, 0, stream>>>(adjH, adjL, Sh, Sl, Xg2r, 2048, 2048);

  gate_kernel<<<2048, 256, 0, stream>>>(x, Xg1f, Xg2r, Wg, gbp, emb, Zf, rb);

  tsplit<<<dim3(32, 32), 256, 0, stream>>>(Zf, Sh, Sl, 2048, 2048);
  fgemm<0, 1><<<dim3(32, 16), 256, 0, stream>>>(adjH, nullptr, Sh, Sl, Cgz1f, 2048, 2048);
  tsplit<<<dim3(32, 32), 256, 0, stream>>>(Cgz1f, Sh, Sl, 2048, 2048);
  fgemm<1, 1><<<dim3(32, 16), 256, 0, stream>>>(adjH, adjL, Sh, Sl, Cgz2r, 2048, 2048);

  wgen<<<dim3(24, 128), 256, 0, stream>>>(Pu, emb, Wu);
  update_kernel<<<2048, 256, 0, stream>>>(x, Zf, Xg1f, Cgz1f, Xg2r, Cgz2r, Wu,
                                          ubp, emb, rb, out);
}